// Round 5
// baseline (254.732 us; speedup 1.0000x reference)
//
#include <hip/hip_runtime.h>
#include <stdint.h>

// B=4, Q=4096, V=4096, H=128, fp32 in/out
#define NBATCH 4
#define NQ 4096
#define NV 4096
#define HD 128

// SCALE * log2(e): scores scaled into exp2 domain (folded into Q fragments)
#define SCL2E ((float)(11.31370849898476 * 1.4426950408889634))

// keep  <=>  bits < 0.9f in fixed point (0.9f = 7549747 * 2^-23)
#define KEEP_THRESH 3865470464u

// skip a (tile,16-row) granule when its max is this far below the best seen
// (64 * 2^-27 < 1e-6, and final per-row l >= 1  =>  contribution < 1e-6 rel.)
#define SKIP_MARGIN 27.0f
// hash dropout only for entries within this of the best seen max
// (2^-20 ~ 1e-6 of the final sum)
#define DROP_MARGIN 20.0f

// --- ws layout (prepass output), FRAG-MAJOR (verified) ---
// per (batch,tile) record: [khi 8192 ush][klo 8192 ush][vt 8192 ush] = 48 KB
// K chunk (kc,nb,lane): (kc*4+nb)*64+lane holds K[v=nb*16+r][kc*32+qd*8..+8]
// V chunk (kc2,n,lane): (kc2*8+n)*64+lane holds V^T[h=n*16+r][kc2*32+qd*8..+8]
#define TILE_USH 24576
#define WS_NEEDED ((size_t)NBATCH * 64 * TILE_USH * 2)       // 12,582,912 B

#define PSTR 72    // pls row stride (ushorts)
#define VLSTR 142  // prepass LDS v-tile stride (ushorts)

// --- fallback path constants (round-3 kernel, verified passing) ---
#define KSTR 144
#define VSTR 76

typedef __attribute__((ext_vector_type(8))) short short8;   // 8 bf16 (MFMA A/B frag)
typedef __attribute__((ext_vector_type(4))) float floatx4;  // MFMA C/D frag
typedef unsigned int uint;
typedef unsigned short ushort;

__device__ __forceinline__ ushort bf16rne(float f) {
    uint u = __float_as_uint(f);
    u = (u + 0x7fffu + ((u >> 16) & 1u)) >> 16;
    return (ushort)u;
}
__device__ __forceinline__ float bf2f(ushort h) {
    return __uint_as_float(((uint)h) << 16);
}

// ---- DPP 16-lane reductions (VALU-only, no DS pipe) ----
template <int CTRL>
__device__ __forceinline__ float dppmov(float x) {
    return __int_as_float(__builtin_amdgcn_update_dpp(
        0, __float_as_int(x), CTRL, 0xF, 0xF, true));
}
__device__ __forceinline__ float row_max16(float x) {
    x = fmaxf(x, dppmov<0xB1>(x));    // quad_perm xor1
    x = fmaxf(x, dppmov<0x4E>(x));    // quad_perm xor2
    x = fmaxf(x, dppmov<0x141>(x));   // row_half_mirror
    x = fmaxf(x, dppmov<0x140>(x));   // row_mirror
    return x;
}
__device__ __forceinline__ float row_sum16(float x) {
    x += dppmov<0xB1>(x);
    x += dppmov<0x4E>(x);
    x += dppmov<0x141>(x);
    x += dppmov<0x140>(x);
    return x;
}

__device__ __forceinline__ uint rotl(uint x, int r) { return (x << r) | (x >> (32 - r)); }

// JAX threefry2x32 partitionable path, key=(0,42): bits = y0 ^ y1 of hash of 64-bit counter j
__device__ __forceinline__ uint threefry_bits(uint j) {
    uint x0 = 0u;   // counter hi word (all j < 2^32)
    uint x1 = j;
    const uint k0 = 0u, k1 = 42u, k2 = 0u ^ 42u ^ 0x1BD11BDAu;
    x0 += k0; x1 += k1;
#define TFR4(a,b,c,d) \
    x0 += x1; x1 = rotl(x1, a); x1 ^= x0; \
    x0 += x1; x1 = rotl(x1, b); x1 ^= x0; \
    x0 += x1; x1 = rotl(x1, c); x1 ^= x0; \
    x0 += x1; x1 = rotl(x1, d); x1 ^= x0;
    TFR4(13, 15, 26, 6)
    x0 += k1; x1 += k2 + 1u;
    TFR4(17, 29, 16, 24)
    x0 += k2; x1 += k0 + 2u;
    TFR4(13, 15, 26, 6)
    x0 += k0; x1 += k1 + 3u;
    TFR4(17, 29, 16, 24)
    x0 += k1; x1 += k2 + 4u;
    TFR4(13, 15, 26, 6)
    x0 += k2; x1 += k0 + 5u;
#undef TFR4
    return x0 ^ x1;
}

// ============================ prepass (byte-identical, verified) ============================
__global__ __launch_bounds__(256)
void prepass(const float* __restrict__ Kg, const float* __restrict__ Vg,
             ushort* __restrict__ W) {
    __shared__ ushort vls[64 * VLSTR];
    const int rec  = blockIdx.x >> 1;
    const int half = blockIdx.x & 1;
    const int bb = rec >> 6;
    const int t  = rec & 63;
    const int v0 = t * 64;
    const size_t kvbase = (size_t)bb * NV * HD;
    ushort* dst = W + ((size_t)bb * 64 + t) * TILE_USH;
    const int tid = threadIdx.x;

    if (half == 0) {
        ushort* dkh = dst;
        ushort* dkl = dst + 8192;
#pragma unroll
        for (int i = 0; i < 4; ++i) {
            int lc = i * 256 + tid;
            int v = lc >> 4, c = lc & 15;
            const float* src = Kg + kvbase + (size_t)(v0 + v) * HD + c * 8;
            float x[8];
            *(float4*)&x[0] = *(const float4*)src;
            *(float4*)&x[4] = *(const float4*)(src + 4);
            uint H[4], L[4];
#pragma unroll
            for (int k = 0; k < 4; ++k) {
                ushort h0 = bf16rne(x[2 * k]),     h1 = bf16rne(x[2 * k + 1]);
                ushort l0 = bf16rne(x[2 * k] - bf2f(h0));
                ushort l1 = bf16rne(x[2 * k + 1] - bf2f(h1));
                H[k] = (uint)h0 | ((uint)h1 << 16);
                L[k] = (uint)l0 | ((uint)l1 << 16);
            }
            int pos = (((c >> 2) * 4 + (v >> 4)) * 64 + (c & 3) * 16 + (v & 15)) * 8;
            *(uint4*)&dkh[pos] = *(uint4*)H;
            *(uint4*)&dkl[pos] = *(uint4*)L;
        }
    } else {
        ushort* dvt = dst + 16384;
#pragma unroll
        for (int i = 0; i < 8; ++i) {
            int idx = i * 256 + tid;
            int v = idx >> 5, hq = idx & 31;
            float4 a = *(const float4*)(Vg + kvbase + (size_t)(v0 + v) * HD + hq * 4);
            uint w0 = (uint)bf16rne(a.x) | ((uint)bf16rne(a.y) << 16);
            uint w1 = (uint)bf16rne(a.z) | ((uint)bf16rne(a.w) << 16);
            *(uint*)&vls[v * VLSTR + hq * 4]     = w0;
            *(uint*)&vls[v * VLSTR + hq * 4 + 2] = w1;
        }
        __syncthreads();
#pragma unroll
        for (int i = 0; i < 4; ++i) {
            int lc = i * 256 + tid;
            int h = lc >> 3, c2 = lc & 7;
            uint Wd[4];
#pragma unroll
            for (int m = 0; m < 8; m += 2) {
                ushort a  = vls[(c2 * 8 + m) * VLSTR + h];
                ushort b2 = vls[(c2 * 8 + m + 1) * VLSTR + h];
                Wd[m >> 1] = (uint)a | ((uint)b2 << 16);
            }
            int pos = (((c2 >> 2) * 8 + (h >> 4)) * 64 + (c2 & 3) * 16 + (h & 15)) * 8;
            *(uint4*)&dvt[pos] = *(uint4*)Wd;
        }
    }
}

// ============================ main (fast path) ============================
// grid 512 x 256 threads (4 waves), 32 q-rows/block — the verified r3 config
// (139us, VGPR 128, no spill). r4 lesson: 16 rows/block halves MFMA-per-load
// amortization and REGRESSES (190us) even with 2x grid; stay at 32 rows.
//
// NEW vs r3: one-tile-ahead QK software pipeline. At iteration t:
//   softmax(t) [VALU]  -- covers the in-flight kc0 loads of tile t+4
//   QK(t+4)    [2-batch ping-pong kc pipeline, writes cf in place (WAR-safe:
//               softmax's cf reads precede in program order); its last load
//               batch prefetches kc0 of tile t+8]
//   PV(t)      [MFMA]  -- QK(t+4)'s MFMAs drain under this + next softmax
// This moves the per-tile L2 load stall (~300cy) under softmax VALU work and
// gives QK MFMAs a full PV+softmax window to complete before their use.
//
// REGISTER BUDGET: (256,2) = 256 unified VGPRs/wave. Live peak ~= qf 64 +
// oacc 64 (AGPR) + cf 32 + K-frags 64 (2 batches, transient) + temps ~= 244.
// w=3 spills catastrophically (r2: 824 MB scratch) — do not raise w.
// If WRITE_SIZE balloons (>200 MB) the pipeline depth must be cut instead.
//
// Fragment layouts (gfx950 mfma_f32_16x16x32_bf16, m89/m120-verified):
//   A: lane holds A[m = lane&15][k = (lane>>4)*8 + j]
//   B: lane holds B[k = (lane>>4)*8 + j][n = lane&15]
//   C/D: lane holds D[row = (lane>>4)*4 + reg][col = lane&15]
__global__ __launch_bounds__(256, 2)
void fa_mfma7(const float* __restrict__ Qg, const ushort* __restrict__ Wk,
              float* __restrict__ Og) {
    __shared__ __align__(16) float smemf[12288];  // 48 KB: pls (loop) | 3x obuf (epilogue)
    __shared__ float mlbuf[3][32][2];             // waves 1-3 partial (m, l)
    __shared__ float gmx[32];                     // per-row best max seen (racy)

    const int tid  = threadIdx.x;
    const int wave = tid >> 6;    // 0..3, tile phase
    const int lane = tid & 63;
    const int r    = lane & 15;
    const int qd   = lane >> 4;
    const int blockRow0 = blockIdx.x * 32;
    const int b = blockRow0 >> 12;
    const ushort* kvw = Wk + (size_t)b * 64 * TILE_USH;
    ushort* pls = (ushort*)smemf + wave * (32 * PSTR);   // per-wave P region

    if (tid < 32) gmx[tid] = -1e30f;

    // Q -> A-fragments for both 16-row m-blocks, PRE-SCALED by SCL2E,
    // hi/lo bf16 split, registers.
    short8 qfh[2][4], qfl[2][4];
#pragma unroll
    for (int mr = 0; mr < 2; ++mr) {
        const float* qp = Qg + (size_t)(blockRow0 + mr * 16 + r) * HD + qd * 8;
#pragma unroll
        for (int kc = 0; kc < 4; ++kc) {
            float x[8];
            *(float4*)&x[0] = *(const float4*)(qp + kc * 32);
            *(float4*)&x[4] = *(const float4*)(qp + kc * 32 + 4);
#pragma unroll
            for (int j = 0; j < 8; ++j) {
                float xs = x[j] * SCL2E;
                ushort h = bf16rne(xs);
                qfh[mr][kc][j] = (short)h;
                qfl[mr][kc][j] = (short)bf16rne(xs - bf2f(h));
            }
        }
    }

    floatx4 oacc[2][8];
#pragma unroll
    for (int mr = 0; mr < 2; ++mr)
#pragma unroll
        for (int n = 0; n < 8; ++n) oacc[mr][n] = (floatx4){0.f, 0.f, 0.f, 0.f};
    float m2[2][4], lr[2][4];
#pragma unroll
    for (int mr = 0; mr < 2; ++mr)
#pragma unroll
        for (int g = 0; g < 4; ++g) { m2[mr][g] = -1e30f; lr[mr][g] = 0.f; }

    __syncthreads();   // gmx initialized

    // ---- QK pipeline machinery ----
    short8 khA[4], klA[4], khB[4], klB[4];
    floatx4 cf[2][4];

#define LOADK(H, L, t_, kc_)                                              \
    {                                                                     \
        const ushort* tKp_ = kvw + (size_t)(t_) * TILE_USH;               \
        _Pragma("unroll")                                                 \
        for (int nb_ = 0; nb_ < 4; ++nb_) {                               \
            const int off_ = (((kc_) * 4 + nb_) * 64 + lane) * 8;         \
            H[nb_] = *(const short8*)&tKp_[off_];                         \
            L[nb_] = *(const short8*)&tKp_[8192 + off_];                  \
        }                                                                 \
    }

#define QKM(kc_, H, L)                                                    \
    {                                                                     \
        _Pragma("unroll")                                                 \
        for (int nb_ = 0; nb_ < 4; ++nb_) {                               \
            _Pragma("unroll")                                             \
            for (int mr_ = 0; mr_ < 2; ++mr_) {                           \
                cf[mr_][nb_] = __builtin_amdgcn_mfma_f32_16x16x32_bf16(   \
                    qfh[mr_][kc_], H[nb_], cf[mr_][nb_], 0, 0, 0);        \
                cf[mr_][nb_] = __builtin_amdgcn_mfma_f32_16x16x32_bf16(   \
                    qfh[mr_][kc_], L[nb_], cf[mr_][nb_], 0, 0, 0);        \
                cf[mr_][nb_] = __builtin_amdgcn_mfma_f32_16x16x32_bf16(   \
                    qfl[mr_][kc_], H[nb_], cf[mr_][nb_], 0, 0, 0);        \
            }                                                             \
        }                                                                 \
    }

    // QK of tile t_; on entry khA/klA hold (t_, kc0); on exit they hold (tpf_, kc0)
#define QKBLOCK(t_, tpf_)                                                 \
    {                                                                     \
        _Pragma("unroll")                                                 \
        for (int mr_ = 0; mr_ < 2; ++mr_) {                               \
            _Pragma("unroll")                                             \
            for (int nb_ = 0; nb_ < 4; ++nb_)                             \
                cf[mr_][nb_] = (floatx4){0.f, 0.f, 0.f, 0.f};             \
        }                                                                 \
        LOADK(khB, klB, t_, 1);   QKM(0, khA, klA);                       \
        LOADK(khA, klA, t_, 2);   QKM(1, khB, klB);                       \
        LOADK(khB, klB, t_, 3);   QKM(2, khA, klA);                       \
        LOADK(khA, klA, tpf_, 0); QKM(3, khB, klB);                       \
    }

    // prologue: QK(wave), leaving kc0 of tile wave+4 in flight
    LOADK(khA, klA, wave, 0);
    QKBLOCK(wave, wave + 4);

    for (int t = wave; t < 64; t += 4) {
        const ushort* tV = kvw + (size_t)t * TILE_USH + 16384;
        const int v0 = t * 64;

        // ---- online softmax on cf = QK(t) (exp2 domain, pre-scaled) ----
        bool act[2];
#pragma unroll
        for (int mr = 0; mr < 2; ++mr) {
            float tmx[4], gm[4];
#pragma unroll
            for (int g = 0; g < 4; ++g) {
                float v = fmaxf(fmaxf(cf[mr][0][g], cf[mr][1][g]),
                                fmaxf(cf[mr][2][g], cf[mr][3][g]));
                tmx[g] = row_max16(v);
            }
            bool rowact = false;
#pragma unroll
            for (int g = 0; g < 4; ++g) {
                gm[g] = gmx[mr * 16 + qd * 4 + g];
                rowact |= (tmx[g] > fmaxf(m2[mr][g], gm[g]) - SKIP_MARGIN);
            }
            // publish (racy; losing a race only loses a skip, never correctness)
#pragma unroll
            for (int g = 0; g < 4; ++g)
                if (r == 0 && tmx[g] > gm[g]) gmx[mr * 16 + qd * 4 + g] = tmx[g];
            act[mr] = __any(rowact);
            if (!act[mr]) continue;   // tile globally negligible for all 16 rows

            // max update + O rescale (only when a new own-max appears)
            float alpha[4];
            bool nm = false;
#pragma unroll
            for (int g = 0; g < 4; ++g) nm |= (tmx[g] > m2[mr][g]);
            if (__any(nm)) {
#pragma unroll
                for (int g = 0; g < 4; ++g) {
                    float mn = fmaxf(m2[mr][g], tmx[g]);
                    alpha[g] = __builtin_amdgcn_exp2f(m2[mr][g] - mn);
                    m2[mr][g] = mn;
                }
#pragma unroll
                for (int n = 0; n < 8; ++n)
#pragma unroll
                    for (int g = 0; g < 4; ++g) oacc[mr][n][g] *= alpha[g];
            } else {
#pragma unroll
                for (int g = 0; g < 4; ++g) alpha[g] = 1.f;
            }

            float p[4][4], thr[4];
#pragma unroll
            for (int g = 0; g < 4; ++g) {
                float s = 0.f;
#pragma unroll
                for (int nb = 0; nb < 4; ++nb) {
                    p[nb][g] = __builtin_amdgcn_exp2f(cf[mr][nb][g] - m2[mr][g]);
                    s += p[nb][g];
                }
                s = row_sum16(s);
                lr[mr][g] = lr[mr][g] * alpha[g] + s;
                thr[g] = fmaxf(gm[g], m2[mr][g]) - DROP_MARGIN;
            }

            // dropout (hash only globally-significant entries); write P for PV
#pragma unroll
            for (int nb = 0; nb < 4; ++nb) {
#pragma unroll
                for (int g = 0; g < 4; ++g) {
                    if (__any(cf[mr][nb][g] > thr[g])) {
                        uint j = (uint)(blockRow0 + mr * 16 + qd * 4 + g) * (uint)NV
                               + (uint)(v0 + nb * 16 + r);
                        if (threefry_bits(j) >= KEEP_THRESH) p[nb][g] = 0.f;
                    }
                    // bf16 truncation (1 op; ~0.2% downward bias, within budget)
                    pls[(mr * 16 + qd * 4 + g) * PSTR + nb * 16 + r] =
                        (ushort)(__float_as_uint(p[nb][g]) >> 16);
                }
            }
        }

        // ---- QK(t+4): overwrites cf (softmax reads done); prefetches (t+8,kc0) ----
        if (t + 4 < 64) {
            const int tn  = t + 4;
            const int tpp = (t + 8 < 64) ? (t + 8) : tn;   // clamp: valid addr, result unused
            QKBLOCK(tn, tpp);
        }

        if (act[0] | act[1]) {
            __asm__ volatile("s_waitcnt lgkmcnt(0)" ::: "memory");  // own-wave P visible
            // ---- PV(t): register-direct V frags, K=32 MFMAs per m-block ----
#pragma unroll
            for (int mr = 0; mr < 2; ++mr) {
                if (!act[mr]) continue;
#pragma unroll
                for (int kc2 = 0; kc2 < 2; ++kc2) {
                    short8 pa = *(const short8*)&pls[(mr * 16 + r) * PSTR + kc2 * 32 + qd * 8];
#pragma unroll
                    for (int n = 0; n < 8; ++n) {
                        short8 vb = *(const short8*)&tV[((kc2 * 8 + n) * 64 + lane) * 8];
                        oacc[mr][n] = __builtin_amdgcn_mfma_f32_16x16x32_bf16(pa, vb, oacc[mr][n], 0, 0, 0);
                    }
                }
            }
        }
    }
#undef QKBLOCK
#undef QKM
#undef LOADK

    // ---- 4-way end merge through the pls-aliased LDS region ----
    __syncthreads();   // all waves done with pls before obuf overwrites it
    if (wave >= 1) {
#pragma unroll
        for (int mr = 0; mr < 2; ++mr) {
            if (r == 0) {
#pragma unroll
                for (int g = 0; g < 4; ++g) {
                    mlbuf[wave - 1][mr * 16 + qd * 4 + g][0] = m2[mr][g];
                    mlbuf[wave - 1][mr * 16 + qd * 4 + g][1] = lr[mr][g];
                }
            }
#pragma unroll
            for (int n = 0; n < 8; ++n)
#pragma unroll
                for (int g = 0; g < 4; ++g)
                    smemf[(wave - 1) * 4096 + (mr * 16 + qd * 4 + g) * 128 + n * 16 + r] =
                        oacc[mr][n][g];
        }
    }
    __syncthreads();
    if (wave == 0) {
#pragma unroll
        for (int mr = 0; mr < 2; ++mr) {
            float a0[4], aw[3][4], inv[4];
#pragma unroll
            for (int g = 0; g < 4; ++g) {
                int row = mr * 16 + qd * 4 + g;
                float mn = m2[mr][g];
#pragma unroll
                for (int i = 0; i < 3; ++i) mn = fmaxf(mn, mlbuf[i][row][0]);
                a0[g] = __builtin_amdgcn_exp2f(m2[mr][g] - mn);
                float l = lr[mr][g] * a0[g];
#pragma unroll
                for (int i = 0; i < 3; ++i) {
                    aw[i][g] = __builtin_amdgcn_exp2f(mlbuf[i][row][0] - mn);
                    l += mlbuf[i][row][1] * aw[i][g];
                }
                inv[g] = 1.0f / (0.9f * l);
            }
#pragma unroll
            for (int n = 0; n < 8; ++n)
#pragma unroll
                for (int g = 0; g < 4; ++g) {
                    int row = mr * 16 + qd * 4 + g;
                    float o = oacc[mr][n][g] * a0[g];
#pragma unroll
                    for (int i = 0; i < 3; ++i)
                        o += smemf[i * 4096 + row * 128 + n * 16 + r] * aw[i][g];
                    Og[(size_t)(blockRow0 + row) * HD + n * 16 + r] = o * inv[g];
                }
        }
    }
}

// ============================ fallback (round-3, verified) ============================
__global__ __launch_bounds__(256)
void fa_mfma(const float* __restrict__ Qg, const float* __restrict__ Kg,
             const float* __restrict__ Vg, float* __restrict__ Og) {
    __shared__ ushort khi[64 * KSTR];
    __shared__ ushort klo[64 * KSTR];
    __shared__ ushort vt[128 * VSTR];
    __shared__ ushort plsf[4][16 * PSTR];

    const int tid  = threadIdx.x;
    const int wave = tid >> 6;
    const int lane = tid & 63;
    const int r    = lane & 15;
    const int qd   = lane >> 4;
    const int blockRow0 = blockIdx.x * 64;
    const int b = blockRow0 >> 12;
    const int waveRow0 = blockRow0 + wave * 16;
    const size_t kvbase = (size_t)b * NV * HD;

    short8 qfh[4], qfl[4];
    {
        const float* qp = Qg + (size_t)(waveRow0 + r) * HD + qd * 8;
#pragma unroll
        for (int kc = 0; kc < 4; ++kc) {
            float x[8];
            *(float4*)&x[0] = *(const float4*)(qp + kc * 32);
            *(float4*)&x[4] = *(const float4*)(qp + kc * 32 + 4);
#pragma unroll
            for (int j = 0; j < 8; ++j) {
                ushort h = bf16rne(x[j]);
                qfh[kc][j] = (short)h;
                qfl[kc][j] = (short)bf16rne(x[j] - bf2f(h));
            }
        }
    }

    floatx4 oacc[8];
#pragma unroll
    for (int n = 0; n < 8; ++n) oacc[n] = (floatx4){0.f, 0.f, 0.f, 0.f};
    float m2[4] = {-INFINITY, -INFINITY, -INFINITY, -INFINITY};
    float lr[4] = {0.f, 0.f, 0.f, 0.f};

    for (int v0 = 0; v0 < NV; v0 += 64) {
        __syncthreads();
#pragma unroll
        for (int i = 0; i < 8; ++i) {
            int f = i * 256 + tid;
            int v = f >> 5;
            int h = (f & 31) * 4;
            float4 kv = *(const float4*)(Kg + kvbase + (size_t)(v0 + v) * HD + h);
            ushort4 hh, ll;
            hh.x = bf16rne(kv.x); ll.x = bf16rne(kv.x - bf2f(hh.x));
            hh.y = bf16rne(kv.y); ll.y = bf16rne(kv.y - bf2f(hh.y));
            hh.z = bf16rne(kv.z); ll.z = bf16rne(kv.z - bf2f(hh.z));
            hh.w = bf16rne(kv.w); ll.w = bf16rne(kv.w - bf2f(hh.w));
            *(ushort4*)&khi[v * KSTR + h] = hh;
            *(ushort4*)&klo[v * KSTR + h] = ll;
        }
        {
            int hp = tid & 63, rp = tid >> 6;
            int h = hp * 2;
            const float* vpb = Vg + kvbase + (size_t)v0 * HD + h;
#pragma unroll
            for (int i = 0; i < 8; ++i) {
                int v = i * 8 + rp * 2;
                float2 a = *(const float2*)(vpb + (size_t)v * HD);
                float2 c = *(const float2*)(vpb + (size_t)(v + 1) * HD);
                uint w0 = (uint)bf16rne(a.x) | ((uint)bf16rne(c.x) << 16);
                uint w1 = (uint)bf16rne(a.y) | ((uint)bf16rne(c.y) << 16);
                *(uint*)&vt[h * VSTR + v]       = w0;
                *(uint*)&vt[(h + 1) * VSTR + v] = w1;
            }
        }
        __syncthreads();

        floatx4 cf[4];
#pragma unroll
        for (int nb = 0; nb < 4; ++nb) cf[nb] = (floatx4){0.f, 0.f, 0.f, 0.f};
#pragma unroll
        for (int kc = 0; kc < 4; ++kc) {
#pragma unroll
            for (int nb = 0; nb < 4; ++nb) {
                int off = (nb * 16 + r) * KSTR + kc * 32 + qd * 8;
                short8 kh = *(const short8*)&khi[off];
                short8 kl = *(const short8*)&klo[off];
                cf[nb] = __builtin_amdgcn_mfma_f32_16x16x32_bf16(qfh[kc], kh, cf[nb], 0, 0, 0);
                cf[nb] = __builtin_amdgcn_mfma_f32_16x16x32_bf16(qfh[kc], kl, cf[nb], 0, 0, 0);
                cf[nb] = __builtin_amdgcn_mfma_f32_16x16x32_bf16(qfl[kc], kh, cf[nb], 0, 0, 0);
            }
        }

        float ts[4][4], p[4][4];
#pragma unroll
        for (int nb = 0; nb < 4; ++nb)
#pragma unroll
            for (int g = 0; g < 4; ++g) ts[nb][g] = cf[nb][g] * SCL2E;

        float tsum[4], alpha[4], lnew[4];
#pragma unroll
        for (int g = 0; g < 4; ++g) {
            float tmx = fmaxf(fmaxf(ts[0][g], ts[1][g]), fmaxf(ts[2][g], ts[3][g]));
#pragma unroll
            for (int off = 1; off < 16; off <<= 1)
                tmx = fmaxf(tmx, __shfl_xor(tmx, off));
            float mn = fmaxf(m2[g], tmx);
            alpha[g] = __builtin_amdgcn_exp2f(m2[g] - mn);
            m2[g] = mn;
        }
#pragma unroll
        for (int g = 0; g < 4; ++g) {
            float s = 0.f;
#pragma unroll
            for (int nb = 0; nb < 4; ++nb) {
                p[nb][g] = __builtin_amdgcn_exp2f(ts[nb][g] - m2[g]);
                s += p[nb][g];
            }
#pragma unroll
            for (int off = 1; off < 16; off <<= 1)
                s += __shfl_xor(s, off);
            tsum[g] = s;
            lnew[g] = lr[g] * alpha[g] + s;
            lr[g] = lnew[g];
        }

        bool rowneed = false;
#pragma unroll
        for (int g = 0; g < 4; ++g) rowneed |= (tsum[g] > 1e-8f * lnew[g]);

        if (__any(rowneed)) {
#pragma unroll
            for (int n = 0; n < 8; ++n)
#pragma unroll
                for (int g = 0; g < 4; ++g) oacc[n][g] *= alpha[g];

#pragma unroll
            for (int nb = 0; nb < 4; ++nb) {
                bool nbneed = false;
#pragma unroll
                for (int g = 0; g < 4; ++g) nbneed |= (p[nb][g] > 1e-8f * lnew[g]);
                if (__any(nbneed)) {
#pragma unroll
                    for (int g = 0; g < 4; ++g) {
                        uint j = (uint)(waveRow0 + qd * 4 + g) * (uint)NV
                               + (uint)(v0 + nb * 16 + r);
                        if (threefry_bits(j) >= KEEP_THRESH) p[nb][g] = 0.f;
                    }
                }
#pragma unroll
                for (int g = 0; g < 4; ++g)
                    plsf[wave][(qd * 4 + g) * PSTR + nb * 16 + r] = bf16rne(p[nb][g]);
            }
            __asm__ volatile("s_waitcnt lgkmcnt(0)" ::: "memory");

#pragma unroll
            for (int kc2 = 0; kc2 < 2; ++kc2) {
                short8 pa = *(const short8*)&plsf[wave][r * PSTR + kc2 * 32 + qd * 8];
#pragma unroll
                for (int n = 0; n < 8; ++n) {
                    int off = (n * 16 + r) * VSTR + kc2 * 32 + qd * 8;
                    ushort4 u0 = *(const ushort4*)&vt[off];
                    ushort4 u1 = *(const ushort4*)&vt[off + 4];
                    short8 vb;
                    vb[0] = (short)u0.x; vb[1] = (short)u0.y; vb[2] = (short)u0.z; vb[3] = (short)u0.w;
                    vb[4] = (short)u1.x; vb[5] = (short)u1.y; vb[6] = (short)u1.z; vb[7] = (short)u1.w;
                    oacc[n] = __builtin_amdgcn_mfma_f32_16x16x32_bf16(pa, vb, oacc[n], 0, 0, 0);
                }
            }
        }
    }

    float inv[4];
#pragma unroll
    for (int g = 0; g < 4; ++g) inv[g] = 1.0f / (0.9f * lr[g]);
#pragma unroll
    for (int n = 0; n < 8; ++n)
#pragma unroll
        for (int g = 0; g < 4; ++g)
            Og[(size_t)(waveRow0 + qd * 4 + g) * HD + n * 16 + r] = oacc[n][g] * inv[g];
}

extern "C" void kernel_launch(void* const* d_in, const int* in_sizes, int n_in,
                              void* d_out, int out_size, void* d_ws, size_t ws_size,
                              hipStream_t stream) {
    (void)in_sizes; (void)n_in; (void)out_size;
    const float* Qg = (const float*)d_in[0];
    const float* Kg = (const float*)d_in[1];
    const float* Vg = (const float*)d_in[2];
    float* Og = (float*)d_out;
    if (ws_size >= WS_NEEDED) {
        ushort* W = (ushort*)d_ws;
        prepass<<<dim3(512), 256, 0, stream>>>(Kg, Vg, W);
        fa_mfma7<<<dim3(NBATCH * NQ / 32), 256, 0, stream>>>(Qg, (const ushort*)W, Og);
    } else {
        fa_mfma<<<dim3(NBATCH * NQ / 64), 256, 0, stream>>>(Qg, Kg, Vg, Og);
    }
}

// Round 6
// 235.174 us; speedup vs baseline: 1.0832x; 1.0832x over previous
//
#include <hip/hip_runtime.h>
#include <stdint.h>

// B=4, Q=4096, V=4096, H=128, fp32 in/out
#define NBATCH 4
#define NQ 4096
#define NV 4096
#define HD 128

// SCALE * log2(e): scores scaled into exp2 domain (folded into Q fragments)
#define SCL2E ((float)(11.31370849898476 * 1.4426950408889634))

// keep  <=>  bits < 0.9f in fixed point (0.9f = 7549747 * 2^-23)
#define KEEP_THRESH 3865470464u

// hh-only screening error bound in exp2 units (|S_hl + S_lh|; stat std ~0.8,
// 12-sigma bound). Used to widen margins so hh-screening stays sound.
#define EBOUND 10.0f
// skip a (tile,16-row) granule when its hh-max is this far below the best seen:
// 27 (true contribution < 64*2^-27 < 1e-6 rel, since final l >= 1) + 2*EBOUND
// (hh_tmx may read low by E; gmx publishes may read high by E).
#define SCREEN_MARGIN 47.0f
// hash dropout only for entries within this of the best seen max: 20 (weight
// < 2^-20 of final sum) + EBOUND for hh-inflated gmx.
#define DROP_MARGIN 30.0f

// --- ws layout (prepass output), FRAG-MAJOR (verified) ---
// per (batch,tile) record: [khi 8192 ush][klo 8192 ush][vt 8192 ush] = 48 KB
// K chunk (kc,nb,lane): (kc*4+nb)*64+lane holds K[v=nb*16+r][kc*32+qd*8..+8]
// V chunk (kc2,n,lane): (kc2*8+n)*64+lane holds V^T[h=n*16+r][kc2*32+qd*8..+8]
#define TILE_USH 24576
#define WS_NEEDED ((size_t)NBATCH * 64 * TILE_USH * 2)       // 12,582,912 B

#define PSTR 72    // pls row stride (ushorts)
#define VLSTR 142  // prepass LDS v-tile stride (ushorts)

// --- fallback path constants (round-3 kernel, verified passing) ---
#define KSTR 144
#define VSTR 76

typedef __attribute__((ext_vector_type(8))) short short8;   // 8 bf16 (MFMA A/B frag)
typedef __attribute__((ext_vector_type(4))) float floatx4;  // MFMA C/D frag
typedef unsigned int uint;
typedef unsigned short ushort;

__device__ __forceinline__ ushort bf16rne(float f) {
    uint u = __float_as_uint(f);
    u = (u + 0x7fffu + ((u >> 16) & 1u)) >> 16;
    return (ushort)u;
}
__device__ __forceinline__ float bf2f(ushort h) {
    return __uint_as_float(((uint)h) << 16);
}

// ---- DPP 16-lane reductions (VALU-only, no DS pipe) ----
template <int CTRL>
__device__ __forceinline__ float dppmov(float x) {
    return __int_as_float(__builtin_amdgcn_update_dpp(
        0, __float_as_int(x), CTRL, 0xF, 0xF, true));
}
__device__ __forceinline__ float row_max16(float x) {
    x = fmaxf(x, dppmov<0xB1>(x));    // quad_perm xor1
    x = fmaxf(x, dppmov<0x4E>(x));    // quad_perm xor2
    x = fmaxf(x, dppmov<0x141>(x));   // row_half_mirror
    x = fmaxf(x, dppmov<0x140>(x));   // row_mirror
    return x;
}
__device__ __forceinline__ float row_sum16(float x) {
    x += dppmov<0xB1>(x);
    x += dppmov<0x4E>(x);
    x += dppmov<0x141>(x);
    x += dppmov<0x140>(x);
    return x;
}

__device__ __forceinline__ uint rotl(uint x, int r) { return (x << r) | (x >> (32 - r)); }

// JAX threefry2x32 partitionable path, key=(0,42): bits = y0 ^ y1 of hash of 64-bit counter j
__device__ __forceinline__ uint threefry_bits(uint j) {
    uint x0 = 0u;   // counter hi word (all j < 2^32)
    uint x1 = j;
    const uint k0 = 0u, k1 = 42u, k2 = 0u ^ 42u ^ 0x1BD11BDAu;
    x0 += k0; x1 += k1;
#define TFR4(a,b,c,d) \
    x0 += x1; x1 = rotl(x1, a); x1 ^= x0; \
    x0 += x1; x1 = rotl(x1, b); x1 ^= x0; \
    x0 += x1; x1 = rotl(x1, c); x1 ^= x0; \
    x0 += x1; x1 = rotl(x1, d); x1 ^= x0;
    TFR4(13, 15, 26, 6)
    x0 += k1; x1 += k2 + 1u;
    TFR4(17, 29, 16, 24)
    x0 += k2; x1 += k0 + 2u;
    TFR4(13, 15, 26, 6)
    x0 += k0; x1 += k1 + 3u;
    TFR4(17, 29, 16, 24)
    x0 += k1; x1 += k2 + 4u;
    TFR4(13, 15, 26, 6)
    x0 += k2; x1 += k0 + 5u;
#undef TFR4
    return x0 ^ x1;
}

// ============================ prepass (byte-identical, verified) ============================
__global__ __launch_bounds__(256)
void prepass(const float* __restrict__ Kg, const float* __restrict__ Vg,
             ushort* __restrict__ W) {
    __shared__ ushort vls[64 * VLSTR];
    const int rec  = blockIdx.x >> 1;
    const int half = blockIdx.x & 1;
    const int bb = rec >> 6;
    const int t  = rec & 63;
    const int v0 = t * 64;
    const size_t kvbase = (size_t)bb * NV * HD;
    ushort* dst = W + ((size_t)bb * 64 + t) * TILE_USH;
    const int tid = threadIdx.x;

    if (half == 0) {
        ushort* dkh = dst;
        ushort* dkl = dst + 8192;
#pragma unroll
        for (int i = 0; i < 4; ++i) {
            int lc = i * 256 + tid;
            int v = lc >> 4, c = lc & 15;
            const float* src = Kg + kvbase + (size_t)(v0 + v) * HD + c * 8;
            float x[8];
            *(float4*)&x[0] = *(const float4*)src;
            *(float4*)&x[4] = *(const float4*)(src + 4);
            uint H[4], L[4];
#pragma unroll
            for (int k = 0; k < 4; ++k) {
                ushort h0 = bf16rne(x[2 * k]),     h1 = bf16rne(x[2 * k + 1]);
                ushort l0 = bf16rne(x[2 * k] - bf2f(h0));
                ushort l1 = bf16rne(x[2 * k + 1] - bf2f(h1));
                H[k] = (uint)h0 | ((uint)h1 << 16);
                L[k] = (uint)l0 | ((uint)l1 << 16);
            }
            int pos = (((c >> 2) * 4 + (v >> 4)) * 64 + (c & 3) * 16 + (v & 15)) * 8;
            *(uint4*)&dkh[pos] = *(uint4*)H;
            *(uint4*)&dkl[pos] = *(uint4*)L;
        }
    } else {
        ushort* dvt = dst + 16384;
#pragma unroll
        for (int i = 0; i < 8; ++i) {
            int idx = i * 256 + tid;
            int v = idx >> 5, hq = idx & 31;
            float4 a = *(const float4*)(Vg + kvbase + (size_t)(v0 + v) * HD + hq * 4);
            uint w0 = (uint)bf16rne(a.x) | ((uint)bf16rne(a.y) << 16);
            uint w1 = (uint)bf16rne(a.z) | ((uint)bf16rne(a.w) << 16);
            *(uint*)&vls[v * VLSTR + hq * 4]     = w0;
            *(uint*)&vls[v * VLSTR + hq * 4 + 2] = w1;
        }
        __syncthreads();
#pragma unroll
        for (int i = 0; i < 4; ++i) {
            int lc = i * 256 + tid;
            int h = lc >> 3, c2 = lc & 7;
            uint Wd[4];
#pragma unroll
            for (int m = 0; m < 8; m += 2) {
                ushort a  = vls[(c2 * 8 + m) * VLSTR + h];
                ushort b2 = vls[(c2 * 8 + m + 1) * VLSTR + h];
                Wd[m >> 1] = (uint)a | ((uint)b2 << 16);
            }
            int pos = (((c2 >> 2) * 8 + (h >> 4)) * 64 + (c2 & 3) * 16 + (h & 15)) * 8;
            *(uint4*)&dvt[pos] = *(uint4*)Wd;
        }
    }
}

// ============================ main (fast path) ============================
// grid 512 x 256 threads (4 waves), 32 q-rows/block — the verified r3 config
// (139us, VGPR 128, no spill). r4: fewer rows/block regresses (amortization).
// r5: manual QK pipelining regresses (compiler's own load hoisting is better;
// keep the simple per-kc loop shape).
//
// NEW vs r3: hh-only QK SCREENING. Steady state (~95% of granules are >27
// exp2-units below the row max and get skipped) previously paid the full
// 3-term QK (96 MFMA + 32 KB K loads) just to discover irrelevance. Now:
//   screen: S_hh only -> 32 MFMA + 16 KB (khi) per tile
//   active (~5-10%): reload khi+klo, add qfh*kl + qfl*kh corrections into the
//     same accumulator -> exact (r3-identical) scores for everything that
//     reaches softmax/dropout/PV.
// Margins widened for the hh error E<=10 (stat 12-sigma): SCREEN_MARGIN=47
// keeps skipped-contribution < 64*2^-27; DROP_MARGIN=30 keeps unhashed
// entries < 2^-20 of the final sum even with hh-inflated gmx publishes.
//
// REGISTER BUDGET: (256,2) = 256 unified VGPRs/wave; w=3 spills (r2: 824 MB
// scratch). Live peak here is LOWER than r3 (transients: 16 VGPR screen /
// 32 correction vs 32 always). DO NOT raise w.
//
// Fragment layouts (gfx950 mfma_f32_16x16x32_bf16, m89/m120-verified):
//   A: lane holds A[m = lane&15][k = (lane>>4)*8 + j]
//   B: lane holds B[k = (lane>>4)*8 + j][n = lane&15]
//   C/D: lane holds D[row = (lane>>4)*4 + reg][col = lane&15]
__global__ __launch_bounds__(256, 2)
void fa_mfma7(const float* __restrict__ Qg, const ushort* __restrict__ Wk,
              float* __restrict__ Og) {
    __shared__ __align__(16) float smemf[12288];  // 48 KB: pls (loop) | 3x obuf (epilogue)
    __shared__ float mlbuf[3][32][2];             // waves 1-3 partial (m, l)
    __shared__ float gmx[32];                     // per-row best max seen (racy)

    const int tid  = threadIdx.x;
    const int wave = tid >> 6;    // 0..3, tile phase
    const int lane = tid & 63;
    const int r    = lane & 15;
    const int qd   = lane >> 4;
    const int blockRow0 = blockIdx.x * 32;
    const int b = blockRow0 >> 12;
    const ushort* kvw = Wk + (size_t)b * 64 * TILE_USH;
    ushort* pls = (ushort*)smemf + wave * (32 * PSTR);   // per-wave P region

    if (tid < 32) gmx[tid] = -1e30f;

    // Q -> A-fragments for both 16-row m-blocks, PRE-SCALED by SCL2E,
    // hi/lo bf16 split, registers.
    short8 qfh[2][4], qfl[2][4];
#pragma unroll
    for (int mr = 0; mr < 2; ++mr) {
        const float* qp = Qg + (size_t)(blockRow0 + mr * 16 + r) * HD + qd * 8;
#pragma unroll
        for (int kc = 0; kc < 4; ++kc) {
            float x[8];
            *(float4*)&x[0] = *(const float4*)(qp + kc * 32);
            *(float4*)&x[4] = *(const float4*)(qp + kc * 32 + 4);
#pragma unroll
            for (int j = 0; j < 8; ++j) {
                float xs = x[j] * SCL2E;
                ushort h = bf16rne(xs);
                qfh[mr][kc][j] = (short)h;
                qfl[mr][kc][j] = (short)bf16rne(xs - bf2f(h));
            }
        }
    }

    floatx4 oacc[2][8];
#pragma unroll
    for (int mr = 0; mr < 2; ++mr)
#pragma unroll
        for (int n = 0; n < 8; ++n) oacc[mr][n] = (floatx4){0.f, 0.f, 0.f, 0.f};
    float m2[2][4], lr[2][4];
#pragma unroll
    for (int mr = 0; mr < 2; ++mr)
#pragma unroll
        for (int g = 0; g < 4; ++g) { m2[mr][g] = -1e30f; lr[mr][g] = 0.f; }

    __syncthreads();   // gmx initialized

    for (int t = wave; t < 64; t += 4) {
        const ushort* tK = kvw + (size_t)t * TILE_USH;
        const ushort* tV = tK + 16384;
        const int v0 = t * 64;

        // ---- hh SCREENING QK(t): khi only, 1 MFMA term ----
        floatx4 cf[2][4];
#pragma unroll
        for (int mr = 0; mr < 2; ++mr)
#pragma unroll
            for (int nb = 0; nb < 4; ++nb) cf[mr][nb] = (floatx4){0.f, 0.f, 0.f, 0.f};
#pragma unroll
        for (int kc = 0; kc < 4; ++kc) {
            short8 kh[4];
#pragma unroll
            for (int nb = 0; nb < 4; ++nb)
                kh[nb] = *(const short8*)&tK[((kc * 4 + nb) * 64 + lane) * 8];
#pragma unroll
            for (int nb = 0; nb < 4; ++nb)
#pragma unroll
                for (int mr = 0; mr < 2; ++mr)
                    cf[mr][nb] = __builtin_amdgcn_mfma_f32_16x16x32_bf16(qfh[mr][kc], kh[nb], cf[mr][nb], 0, 0, 0);
        }

        // ---- screen decision on hh scores ----
        bool sact[2];
        float gm[2][4];
#pragma unroll
        for (int mr = 0; mr < 2; ++mr) {
            float tmx[4];
#pragma unroll
            for (int g = 0; g < 4; ++g) {
                float v = fmaxf(fmaxf(cf[mr][0][g], cf[mr][1][g]),
                                fmaxf(cf[mr][2][g], cf[mr][3][g]));
                tmx[g] = row_max16(v);
            }
            bool rowact = false;
#pragma unroll
            for (int g = 0; g < 4; ++g) {
                gm[mr][g] = gmx[mr * 16 + qd * 4 + g];
                rowact |= (tmx[g] > fmaxf(m2[mr][g], gm[mr][g]) - SCREEN_MARGIN);
            }
            // publish hh-based max (racy, may read high/low by <=E; margins absorb)
#pragma unroll
            for (int g = 0; g < 4; ++g)
                if (r == 0 && tmx[g] > gm[mr][g]) gmx[mr * 16 + qd * 4 + g] = tmx[g];
            sact[mr] = __any(rowact);
        }

        if (sact[0] | sact[1]) {
            // ---- correction pass: exact scores for active m-blocks ----
#pragma unroll
            for (int kc = 0; kc < 4; ++kc) {
                short8 kh[4], kl[4];
#pragma unroll
                for (int nb = 0; nb < 4; ++nb) {
                    int off = ((kc * 4 + nb) * 64 + lane) * 8;
                    kh[nb] = *(const short8*)&tK[off];
                    kl[nb] = *(const short8*)&tK[8192 + off];
                }
#pragma unroll
                for (int nb = 0; nb < 4; ++nb)
#pragma unroll
                    for (int mr = 0; mr < 2; ++mr)
                        if (sact[mr]) {
                            cf[mr][nb] = __builtin_amdgcn_mfma_f32_16x16x32_bf16(qfh[mr][kc], kl[nb], cf[mr][nb], 0, 0, 0);
                            cf[mr][nb] = __builtin_amdgcn_mfma_f32_16x16x32_bf16(qfl[mr][kc], kh[nb], cf[mr][nb], 0, 0, 0);
                        }
            }

            // ---- online softmax on corrected scores, per active m-block ----
#pragma unroll
            for (int mr = 0; mr < 2; ++mr) {
                if (!sact[mr]) continue;
                float ctx[4];
#pragma unroll
                for (int g = 0; g < 4; ++g) {
                    float v = fmaxf(fmaxf(cf[mr][0][g], cf[mr][1][g]),
                                    fmaxf(cf[mr][2][g], cf[mr][3][g]));
                    ctx[g] = row_max16(v);
                }
                // max update + O rescale (only when a new own-max appears)
                float alpha[4];
                bool nm = false;
#pragma unroll
                for (int g = 0; g < 4; ++g) nm |= (ctx[g] > m2[mr][g]);
                if (__any(nm)) {
#pragma unroll
                    for (int g = 0; g < 4; ++g) {
                        float mn = fmaxf(m2[mr][g], ctx[g]);
                        alpha[g] = __builtin_amdgcn_exp2f(m2[mr][g] - mn);
                        m2[mr][g] = mn;
                    }
#pragma unroll
                    for (int n = 0; n < 8; ++n)
#pragma unroll
                        for (int g = 0; g < 4; ++g) oacc[mr][n][g] *= alpha[g];
                } else {
#pragma unroll
                    for (int g = 0; g < 4; ++g) alpha[g] = 1.f;
                }

                float p[4][4], thr[4];
#pragma unroll
                for (int g = 0; g < 4; ++g) {
                    float s = 0.f;
#pragma unroll
                    for (int nb = 0; nb < 4; ++nb) {
                        p[nb][g] = __builtin_amdgcn_exp2f(cf[mr][nb][g] - m2[mr][g]);
                        s += p[nb][g];
                    }
                    s = row_sum16(s);
                    lr[mr][g] = lr[mr][g] * alpha[g] + s;
                    thr[g] = fmaxf(gm[mr][g], m2[mr][g]) - DROP_MARGIN;
                }

                // dropout (hash only globally-significant entries); write P for PV
#pragma unroll
                for (int nb = 0; nb < 4; ++nb) {
#pragma unroll
                    for (int g = 0; g < 4; ++g) {
                        if (__any(cf[mr][nb][g] > thr[g])) {
                            uint j = (uint)(blockRow0 + mr * 16 + qd * 4 + g) * (uint)NV
                                   + (uint)(v0 + nb * 16 + r);
                            if (threefry_bits(j) >= KEEP_THRESH) p[nb][g] = 0.f;
                        }
                        // bf16 truncation (1 op; ~0.2% downward bias, within budget)
                        pls[(mr * 16 + qd * 4 + g) * PSTR + nb * 16 + r] =
                            (ushort)(__float_as_uint(p[nb][g]) >> 16);
                    }
                }
            }

            __asm__ volatile("s_waitcnt lgkmcnt(0)" ::: "memory");  // own-wave P visible
            // ---- PV(t): register-direct V frags, K=32 MFMAs per active m-block ----
#pragma unroll
            for (int mr = 0; mr < 2; ++mr) {
                if (!sact[mr]) continue;
#pragma unroll
                for (int kc2 = 0; kc2 < 2; ++kc2) {
                    short8 pa = *(const short8*)&pls[(mr * 16 + r) * PSTR + kc2 * 32 + qd * 8];
#pragma unroll
                    for (int n = 0; n < 8; ++n) {
                        short8 vb = *(const short8*)&tV[((kc2 * 8 + n) * 64 + lane) * 8];
                        oacc[mr][n] = __builtin_amdgcn_mfma_f32_16x16x32_bf16(pa, vb, oacc[mr][n], 0, 0, 0);
                    }
                }
            }
        }
    }

    // ---- 4-way end merge through the pls-aliased LDS region ----
    __syncthreads();   // all waves done with pls before obuf overwrites it
    if (wave >= 1) {
#pragma unroll
        for (int mr = 0; mr < 2; ++mr) {
            if (r == 0) {
#pragma unroll
                for (int g = 0; g < 4; ++g) {
                    mlbuf[wave - 1][mr * 16 + qd * 4 + g][0] = m2[mr][g];
                    mlbuf[wave - 1][mr * 16 + qd * 4 + g][1] = lr[mr][g];
                }
            }
#pragma unroll
            for (int n = 0; n < 8; ++n)
#pragma unroll
                for (int g = 0; g < 4; ++g)
                    smemf[(wave - 1) * 4096 + (mr * 16 + qd * 4 + g) * 128 + n * 16 + r] =
                        oacc[mr][n][g];
        }
    }
    __syncthreads();
    if (wave == 0) {
#pragma unroll
        for (int mr = 0; mr < 2; ++mr) {
            float a0[4], aw[3][4], inv[4];
#pragma unroll
            for (int g = 0; g < 4; ++g) {
                int row = mr * 16 + qd * 4 + g;
                float mn = m2[mr][g];
#pragma unroll
                for (int i = 0; i < 3; ++i) mn = fmaxf(mn, mlbuf[i][row][0]);
                a0[g] = __builtin_amdgcn_exp2f(m2[mr][g] - mn);
                float l = lr[mr][g] * a0[g];
#pragma unroll
                for (int i = 0; i < 3; ++i) {
                    aw[i][g] = __builtin_amdgcn_exp2f(mlbuf[i][row][0] - mn);
                    l += mlbuf[i][row][1] * aw[i][g];
                }
                inv[g] = 1.0f / (0.9f * l);
            }
#pragma unroll
            for (int n = 0; n < 8; ++n)
#pragma unroll
                for (int g = 0; g < 4; ++g) {
                    int row = mr * 16 + qd * 4 + g;
                    float o = oacc[mr][n][g] * a0[g];
#pragma unroll
                    for (int i = 0; i < 3; ++i)
                        o += smemf[i * 4096 + row * 128 + n * 16 + r] * aw[i][g];
                    Og[(size_t)(blockRow0 + row) * HD + n * 16 + r] = o * inv[g];
                }
        }
    }
}

// ============================ fallback (round-3, verified) ============================
__global__ __launch_bounds__(256)
void fa_mfma(const float* __restrict__ Qg, const float* __restrict__ Kg,
             const float* __restrict__ Vg, float* __restrict__ Og) {
    __shared__ ushort khi[64 * KSTR];
    __shared__ ushort klo[64 * KSTR];
    __shared__ ushort vt[128 * VSTR];
    __shared__ ushort plsf[4][16 * PSTR];

    const int tid  = threadIdx.x;
    const int wave = tid >> 6;
    const int lane = tid & 63;
    const int r    = lane & 15;
    const int qd   = lane >> 4;
    const int blockRow0 = blockIdx.x * 64;
    const int b = blockRow0 >> 12;
    const int waveRow0 = blockRow0 + wave * 16;
    const size_t kvbase = (size_t)b * NV * HD;

    short8 qfh[4], qfl[4];
    {
        const float* qp = Qg + (size_t)(waveRow0 + r) * HD + qd * 8;
#pragma unroll
        for (int kc = 0; kc < 4; ++kc) {
            float x[8];
            *(float4*)&x[0] = *(const float4*)(qp + kc * 32);
            *(float4*)&x[4] = *(const float4*)(qp + kc * 32 + 4);
#pragma unroll
            for (int j = 0; j < 8; ++j) {
                ushort h = bf16rne(x[j]);
                qfh[kc][j] = (short)h;
                qfl[kc][j] = (short)bf16rne(x[j] - bf2f(h));
            }
        }
    }

    floatx4 oacc[8];
#pragma unroll
    for (int n = 0; n < 8; ++n) oacc[n] = (floatx4){0.f, 0.f, 0.f, 0.f};
    float m2[4] = {-INFINITY, -INFINITY, -INFINITY, -INFINITY};
    float lr[4] = {0.f, 0.f, 0.f, 0.f};

    for (int v0 = 0; v0 < NV; v0 += 64) {
        __syncthreads();
#pragma unroll
        for (int i = 0; i < 8; ++i) {
            int f = i * 256 + tid;
            int v = f >> 5;
            int h = (f & 31) * 4;
            float4 kv = *(const float4*)(Kg + kvbase + (size_t)(v0 + v) * HD + h);
            ushort4 hh, ll;
            hh.x = bf16rne(kv.x); ll.x = bf16rne(kv.x - bf2f(hh.x));
            hh.y = bf16rne(kv.y); ll.y = bf16rne(kv.y - bf2f(hh.y));
            hh.z = bf16rne(kv.z); ll.z = bf16rne(kv.z - bf2f(hh.z));
            hh.w = bf16rne(kv.w); ll.w = bf16rne(kv.w - bf2f(hh.w));
            *(ushort4*)&khi[v * KSTR + h] = hh;
            *(ushort4*)&klo[v * KSTR + h] = ll;
        }
        {
            int hp = tid & 63, rp = tid >> 6;
            int h = hp * 2;
            const float* vpb = Vg + kvbase + (size_t)v0 * HD + h;
#pragma unroll
            for (int i = 0; i < 8; ++i) {
                int v = i * 8 + rp * 2;
                float2 a = *(const float2*)(vpb + (size_t)v * HD);
                float2 c = *(const float2*)(vpb + (size_t)(v + 1) * HD);
                uint w0 = (uint)bf16rne(a.x) | ((uint)bf16rne(c.x) << 16);
                uint w1 = (uint)bf16rne(a.y) | ((uint)bf16rne(c.y) << 16);
                *(uint*)&vt[h * VSTR + v]       = w0;
                *(uint*)&vt[(h + 1) * VSTR + v] = w1;
            }
        }
        __syncthreads();

        floatx4 cf[4];
#pragma unroll
        for (int nb = 0; nb < 4; ++nb) cf[nb] = (floatx4){0.f, 0.f, 0.f, 0.f};
#pragma unroll
        for (int kc = 0; kc < 4; ++kc) {
#pragma unroll
            for (int nb = 0; nb < 4; ++nb) {
                int off = (nb * 16 + r) * KSTR + kc * 32 + qd * 8;
                short8 kh = *(const short8*)&khi[off];
                short8 kl = *(const short8*)&klo[off];
                cf[nb] = __builtin_amdgcn_mfma_f32_16x16x32_bf16(qfh[kc], kh, cf[nb], 0, 0, 0);
                cf[nb] = __builtin_amdgcn_mfma_f32_16x16x32_bf16(qfh[kc], kl, cf[nb], 0, 0, 0);
                cf[nb] = __builtin_amdgcn_mfma_f32_16x16x32_bf16(qfl[kc], kh, cf[nb], 0, 0, 0);
            }
        }

        float ts[4][4], p[4][4];
#pragma unroll
        for (int nb = 0; nb < 4; ++nb)
#pragma unroll
            for (int g = 0; g < 4; ++g) ts[nb][g] = cf[nb][g] * SCL2E;

        float tsum[4], alpha[4], lnew[4];
#pragma unroll
        for (int g = 0; g < 4; ++g) {
            float tmx = fmaxf(fmaxf(ts[0][g], ts[1][g]), fmaxf(ts[2][g], ts[3][g]));
#pragma unroll
            for (int off = 1; off < 16; off <<= 1)
                tmx = fmaxf(tmx, __shfl_xor(tmx, off));
            float mn = fmaxf(m2[g], tmx);
            alpha[g] = __builtin_amdgcn_exp2f(m2[g] - mn);
            m2[g] = mn;
        }
#pragma unroll
        for (int g = 0; g < 4; ++g) {
            float s = 0.f;
#pragma unroll
            for (int nb = 0; nb < 4; ++nb) {
                p[nb][g] = __builtin_amdgcn_exp2f(ts[nb][g] - m2[g]);
                s += p[nb][g];
            }
#pragma unroll
            for (int off = 1; off < 16; off <<= 1)
                s += __shfl_xor(s, off);
            tsum[g] = s;
            lnew[g] = lr[g] * alpha[g] + s;
            lr[g] = lnew[g];
        }

        bool rowneed = false;
#pragma unroll
        for (int g = 0; g < 4; ++g) rowneed |= (tsum[g] > 1e-8f * lnew[g]);

        if (__any(rowneed)) {
#pragma unroll
            for (int n = 0; n < 8; ++n)
#pragma unroll
                for (int g = 0; g < 4; ++g) oacc[n][g] *= alpha[g];

#pragma unroll
            for (int nb = 0; nb < 4; ++nb) {
                bool nbneed = false;
#pragma unroll
                for (int g = 0; g < 4; ++g) nbneed |= (p[nb][g] > 1e-8f * lnew[g]);
                if (__any(nbneed)) {
#pragma unroll
                    for (int g = 0; g < 4; ++g) {
                        uint j = (uint)(waveRow0 + qd * 4 + g) * (uint)NV
                               + (uint)(v0 + nb * 16 + r);
                        if (threefry_bits(j) >= KEEP_THRESH) p[nb][g] = 0.f;
                    }
                }
#pragma unroll
                for (int g = 0; g < 4; ++g)
                    plsf[wave][(qd * 4 + g) * PSTR + nb * 16 + r] = bf16rne(p[nb][g]);
            }
            __asm__ volatile("s_waitcnt lgkmcnt(0)" ::: "memory");

#pragma unroll
            for (int kc2 = 0; kc2 < 2; ++kc2) {
                short8 pa = *(const short8*)&plsf[wave][r * PSTR + kc2 * 32 + qd * 8];
#pragma unroll
                for (int n = 0; n < 8; ++n) {
                    int off = (n * 16 + r) * VSTR + kc2 * 32 + qd * 8;
                    ushort4 u0 = *(const ushort4*)&vt[off];
                    ushort4 u1 = *(const ushort4*)&vt[off + 4];
                    short8 vb;
                    vb[0] = (short)u0.x; vb[1] = (short)u0.y; vb[2] = (short)u0.z; vb[3] = (short)u0.w;
                    vb[4] = (short)u1.x; vb[5] = (short)u1.y; vb[6] = (short)u1.z; vb[7] = (short)u1.w;
                    oacc[n] = __builtin_amdgcn_mfma_f32_16x16x32_bf16(pa, vb, oacc[n], 0, 0, 0);
                }
            }
        }
    }

    float inv[4];
#pragma unroll
    for (int g = 0; g < 4; ++g) inv[g] = 1.0f / (0.9f * lr[g]);
#pragma unroll
    for (int n = 0; n < 8; ++n)
#pragma unroll
        for (int g = 0; g < 4; ++g)
            Og[(size_t)(waveRow0 + qd * 4 + g) * HD + n * 16 + r] = oacc[n][g] * inv[g];
}

extern "C" void kernel_launch(void* const* d_in, const int* in_sizes, int n_in,
                              void* d_out, int out_size, void* d_ws, size_t ws_size,
                              hipStream_t stream) {
    (void)in_sizes; (void)n_in; (void)out_size;
    const float* Qg = (const float*)d_in[0];
    const float* Kg = (const float*)d_in[1];
    const float* Vg = (const float*)d_in[2];
    float* Og = (float*)d_out;
    if (ws_size >= WS_NEEDED) {
        ushort* W = (ushort*)d_ws;
        prepass<<<dim3(512), 256, 0, stream>>>(Kg, Vg, W);
        fa_mfma7<<<dim3(NBATCH * NQ / 32), 256, 0, stream>>>(Qg, (const ushort*)W, Og);
    } else {
        fa_mfma<<<dim3(NBATCH * NQ / 64), 256, 0, stream>>>(Qg, Kg, Vg, Og);
    }
}

// Round 7
// 200.047 us; speedup vs baseline: 1.2734x; 1.1756x over previous
//
#include <hip/hip_runtime.h>
#include <stdint.h>

// B=4, Q=4096, V=4096, H=128, fp32 in/out
#define NBATCH 4
#define NQ 4096
#define NV 4096
#define HD 128

// SCALE * log2(e): scores scaled into exp2 domain (folded into Q fragments)
#define SCL2E ((float)(11.31370849898476 * 1.4426950408889634))

// keep  <=>  bits < 0.9f in fixed point (0.9f = 7549747 * 2^-23)
#define KEEP_THRESH 3865470464u

// skip a (tile,16-row) granule when its max is this far below the best seen
// (64 * 2^-27 < 1e-6, and final per-row l >= 1  =>  contribution < 1e-6 rel.)
#define SKIP_MARGIN 27.0f
// hash dropout only for entries within this of the best seen max
// (2^-20 ~ 1e-6 of the final sum)
#define DROP_MARGIN 20.0f

// --- ws layout (prepass output), FRAG-MAJOR (verified) ---
// per (batch,tile) record: [khi 8192 ush][klo 8192 ush][vt 8192 ush] = 48 KB
// K chunk (kc,nb,lane): (kc*4+nb)*64+lane holds K[v=nb*16+r][kc*32+qd*8..+8]
// V chunk (kc2,n,lane): (kc2*8+n)*64+lane holds V^T[h=n*16+r][kc2*32+qd*8..+8]
#define TILE_USH 24576
#define WS_NEEDED ((size_t)NBATCH * 64 * TILE_USH * 2)       // 12,582,912 B

#define PSTR 72    // pls row stride (ushorts)
#define VQS 34     // prepass LDS v-slice stride (32 h + 2 pad, ushorts)

// --- fallback path constants (round-3 kernel, verified passing) ---
#define KSTR 144
#define VSTR 76

typedef __attribute__((ext_vector_type(8))) short short8;   // 8 bf16 (MFMA A/B frag)
typedef __attribute__((ext_vector_type(4))) float floatx4;  // MFMA C/D frag
typedef unsigned int uint;
typedef unsigned short ushort;

__device__ __forceinline__ ushort bf16rne(float f) {
    uint u = __float_as_uint(f);
    u = (u + 0x7fffu + ((u >> 16) & 1u)) >> 16;
    return (ushort)u;
}
__device__ __forceinline__ float bf2f(ushort h) {
    return __uint_as_float(((uint)h) << 16);
}

// ---- DPP 16-lane reductions (VALU-only, no DS pipe) ----
template <int CTRL>
__device__ __forceinline__ float dppmov(float x) {
    return __int_as_float(__builtin_amdgcn_update_dpp(
        0, __float_as_int(x), CTRL, 0xF, 0xF, true));
}
__device__ __forceinline__ float row_max16(float x) {
    x = fmaxf(x, dppmov<0xB1>(x));    // quad_perm xor1
    x = fmaxf(x, dppmov<0x4E>(x));    // quad_perm xor2
    x = fmaxf(x, dppmov<0x141>(x));   // row_half_mirror
    x = fmaxf(x, dppmov<0x140>(x));   // row_mirror
    return x;
}
__device__ __forceinline__ float row_sum16(float x) {
    x += dppmov<0xB1>(x);
    x += dppmov<0x4E>(x);
    x += dppmov<0x141>(x);
    x += dppmov<0x140>(x);
    return x;
}

__device__ __forceinline__ uint rotl(uint x, int r) { return (x << r) | (x >> (32 - r)); }

// JAX threefry2x32 partitionable path, key=(0,42): bits = y0 ^ y1 of hash of 64-bit counter j
__device__ __forceinline__ uint threefry_bits(uint j) {
    uint x0 = 0u;   // counter hi word (all j < 2^32)
    uint x1 = j;
    const uint k0 = 0u, k1 = 42u, k2 = 0u ^ 42u ^ 0x1BD11BDAu;
    x0 += k0; x1 += k1;
#define TFR4(a,b,c,d) \
    x0 += x1; x1 = rotl(x1, a); x1 ^= x0; \
    x0 += x1; x1 = rotl(x1, b); x1 ^= x0; \
    x0 += x1; x1 = rotl(x1, c); x1 ^= x0; \
    x0 += x1; x1 = rotl(x1, d); x1 ^= x0;
    TFR4(13, 15, 26, 6)
    x0 += k1; x1 += k2 + 1u;
    TFR4(17, 29, 16, 24)
    x0 += k2; x1 += k0 + 2u;
    TFR4(13, 15, 26, 6)
    x0 += k0; x1 += k1 + 3u;
    TFR4(17, 29, 16, 24)
    x0 += k1; x1 += k2 + 4u;
    TFR4(13, 15, 26, 6)
    x0 += k2; x1 += k0 + 5u;
#undef TFR4
    return x0 ^ x1;
}

// ============================ prepass (4x finer grid; output bytes identical) ============================
// r6 insight: total - fa_mfma7 ~= 57us every round; prepass moves only ~29 MB
// (~5us of HBM) but ran at 512 blocks = 2 blocks/CU, latency-bound. Split each
// (rec, half) into 4 quarter-blocks -> grid 2048, 8 blocks/CU. K quarters take
// one 256-thread chunk each; V quarters own a 32-column h-slice (2 load iters
// into a [64][34] LDS slice + 1 transpose-write iter). W layout unchanged.
__global__ __launch_bounds__(256)
void prepass(const float* __restrict__ Kg, const float* __restrict__ Vg,
             ushort* __restrict__ W) {
    __shared__ ushort vls[64 * VQS];
    const int unit = blockIdx.x;          // 0..2047
    const int q    = unit & 3;
    const int half = (unit >> 2) & 1;
    const int rec  = unit >> 3;           // 0..255
    const int bb = rec >> 6;
    const int t  = rec & 63;
    const int v0 = t * 64;
    const size_t kvbase = (size_t)bb * NV * HD;
    ushort* dst = W + ((size_t)bb * 64 + t) * TILE_USH;
    const int tid = threadIdx.x;

    if (half == 0) {
        ushort* dkh = dst;
        ushort* dkl = dst + 8192;
        int lc = q * 256 + tid;
        int v = lc >> 4, c = lc & 15;
        const float* src = Kg + kvbase + (size_t)(v0 + v) * HD + c * 8;
        float x[8];
        *(float4*)&x[0] = *(const float4*)src;
        *(float4*)&x[4] = *(const float4*)(src + 4);
        uint H[4], L[4];
#pragma unroll
        for (int k = 0; k < 4; ++k) {
            ushort h0 = bf16rne(x[2 * k]),     h1 = bf16rne(x[2 * k + 1]);
            ushort l0 = bf16rne(x[2 * k] - bf2f(h0));
            ushort l1 = bf16rne(x[2 * k + 1] - bf2f(h1));
            H[k] = (uint)h0 | ((uint)h1 << 16);
            L[k] = (uint)l0 | ((uint)l1 << 16);
        }
        int pos = (((c >> 2) * 4 + (v >> 4)) * 64 + (c & 3) * 16 + (v & 15)) * 8;
        *(uint4*)&dkh[pos] = *(uint4*)H;
        *(uint4*)&dkl[pos] = *(uint4*)L;
    } else {
        ushort* dvt = dst + 16384;
        // load this quarter's h-slice: hq in [q*8, q*8+8), i.e. h in [q*32, q*32+32)
#pragma unroll
        for (int i = 0; i < 2; ++i) {
            int idx = i * 256 + tid;      // 0..511
            int v = idx >> 3, hql = idx & 7;
            int hq = q * 8 + hql;
            float4 a = *(const float4*)(Vg + kvbase + (size_t)(v0 + v) * HD + hq * 4);
            uint w0 = (uint)bf16rne(a.x) | ((uint)bf16rne(a.y) << 16);
            uint w1 = (uint)bf16rne(a.z) | ((uint)bf16rne(a.w) << 16);
            *(uint*)&vls[v * VQS + hql * 4]     = w0;
            *(uint*)&vls[v * VQS + hql * 4 + 2] = w1;
        }
        __syncthreads();
        // transpose-write: hl = local h (0..31), c2 = v-octet (0..7)
        int hl = tid >> 3, c2 = tid & 7;
        int h = q * 32 + hl;
        uint Wd[4];
#pragma unroll
        for (int m = 0; m < 8; m += 2) {
            ushort a  = vls[(c2 * 8 + m) * VQS + hl];
            ushort b2 = vls[(c2 * 8 + m + 1) * VQS + hl];
            Wd[m >> 1] = (uint)a | ((uint)b2 << 16);
        }
        int pos = (((c2 >> 2) * 8 + (h >> 4)) * 64 + (c2 & 3) * 16 + (h & 15)) * 8;
        *(uint4*)&dvt[pos] = *(uint4*)Wd;
    }
}

// ============================ main (fast path, byte-identical to round 3) ============================
// grid 512 x 256 threads (4 waves), 32 q-rows/block, tiles t = wave (mod 4),
// no barriers in the K-loop, all MFMA operands register-direct from frag-major W.
//
// REGISTER BUDGET (hard-won): __launch_bounds__(256,2) = 2 waves/SIMD = 256
// unified VGPRs/wave. Live state ~190: fits at w=2 (128 arch VGPRs, zero
// spill), spills catastrophically at w=3/w=4 (r1/r2: 0.8-1.6 GB scratch).
// STRUCTURAL LESSONS (r4/r5/r6): 16 rows/block regresses (amortization);
// manual QK pipelining regresses (compiler hoists loads better); hh-screening
// regresses (extra dependent phase lengthens the latency-bound critical path).
// This shape is a local optimum at 2 waves/SIMD.
//
// VALU cuts (verified r3): gmx racy skip, absolute-score dropout gate,
// SCL2E folded into Q, O-rescale only on new max, pls->obuf LDS alias.
// Fragment layouts (gfx950 mfma_f32_16x16x32_bf16, m89/m120-verified):
//   A: lane holds A[m = lane&15][k = (lane>>4)*8 + j]
//   B: lane holds B[k = (lane>>4)*8 + j][n = lane&15]
//   C/D: lane holds D[row = (lane>>4)*4 + reg][col = lane&15]
__global__ __launch_bounds__(256, 2)
void fa_mfma7(const float* __restrict__ Qg, const ushort* __restrict__ Wk,
              float* __restrict__ Og) {
    __shared__ __align__(16) float smemf[12288];  // 48 KB: pls (loop) | 3x obuf (epilogue)
    __shared__ float mlbuf[3][32][2];             // waves 1-3 partial (m, l)
    __shared__ float gmx[32];                     // per-row best max seen (racy)

    const int tid  = threadIdx.x;
    const int wave = tid >> 6;    // 0..3, tile phase
    const int lane = tid & 63;
    const int r    = lane & 15;
    const int qd   = lane >> 4;
    const int blockRow0 = blockIdx.x * 32;
    const int b = blockRow0 >> 12;
    const ushort* kvw = Wk + (size_t)b * 64 * TILE_USH;
    ushort* pls = (ushort*)smemf + wave * (32 * PSTR);   // per-wave P region

    if (tid < 32) gmx[tid] = -1e30f;

    // Q -> A-fragments for both 16-row m-blocks, PRE-SCALED by SCL2E,
    // hi/lo bf16 split, registers.
    short8 qfh[2][4], qfl[2][4];
#pragma unroll
    for (int mr = 0; mr < 2; ++mr) {
        const float* qp = Qg + (size_t)(blockRow0 + mr * 16 + r) * HD + qd * 8;
#pragma unroll
        for (int kc = 0; kc < 4; ++kc) {
            float x[8];
            *(float4*)&x[0] = *(const float4*)(qp + kc * 32);
            *(float4*)&x[4] = *(const float4*)(qp + kc * 32 + 4);
#pragma unroll
            for (int j = 0; j < 8; ++j) {
                float xs = x[j] * SCL2E;
                ushort h = bf16rne(xs);
                qfh[mr][kc][j] = (short)h;
                qfl[mr][kc][j] = (short)bf16rne(xs - bf2f(h));
            }
        }
    }

    floatx4 oacc[2][8];
#pragma unroll
    for (int mr = 0; mr < 2; ++mr)
#pragma unroll
        for (int n = 0; n < 8; ++n) oacc[mr][n] = (floatx4){0.f, 0.f, 0.f, 0.f};
    float m2[2][4], lr[2][4];
#pragma unroll
    for (int mr = 0; mr < 2; ++mr)
#pragma unroll
        for (int g = 0; g < 4; ++g) { m2[mr][g] = -1e30f; lr[mr][g] = 0.f; }

    __syncthreads();   // gmx initialized

    for (int t = wave; t < 64; t += 4) {
        const ushort* tK = kvw + (size_t)t * TILE_USH;
        const ushort* tV = tK + 16384;
        const int v0 = t * 64;

        // ---- QK^T(t): register-direct loads, 3-term bf16-split, both m-blocks ----
        floatx4 cf[2][4];
#pragma unroll
        for (int mr = 0; mr < 2; ++mr)
#pragma unroll
            for (int nb = 0; nb < 4; ++nb) cf[mr][nb] = (floatx4){0.f, 0.f, 0.f, 0.f};
#pragma unroll
        for (int kc = 0; kc < 4; ++kc) {
            short8 kh[4], kl[4];
#pragma unroll
            for (int nb = 0; nb < 4; ++nb) {
                int off = ((kc * 4 + nb) * 64 + lane) * 8;
                kh[nb] = *(const short8*)&tK[off];
                kl[nb] = *(const short8*)&tK[8192 + off];
            }
#pragma unroll
            for (int nb = 0; nb < 4; ++nb)
#pragma unroll
                for (int mr = 0; mr < 2; ++mr) {
                    cf[mr][nb] = __builtin_amdgcn_mfma_f32_16x16x32_bf16(qfh[mr][kc], kh[nb], cf[mr][nb], 0, 0, 0);
                    cf[mr][nb] = __builtin_amdgcn_mfma_f32_16x16x32_bf16(qfh[mr][kc], kl[nb], cf[mr][nb], 0, 0, 0);
                    cf[mr][nb] = __builtin_amdgcn_mfma_f32_16x16x32_bf16(qfl[mr][kc], kh[nb], cf[mr][nb], 0, 0, 0);
                }
        }

        // ---- online softmax (exp2 domain, scores pre-scaled), per m-block ----
        bool act[2];
#pragma unroll
        for (int mr = 0; mr < 2; ++mr) {
            float tmx[4], gm[4];
#pragma unroll
            for (int g = 0; g < 4; ++g) {
                float v = fmaxf(fmaxf(cf[mr][0][g], cf[mr][1][g]),
                                fmaxf(cf[mr][2][g], cf[mr][3][g]));
                tmx[g] = row_max16(v);
            }
            bool rowact = false;
#pragma unroll
            for (int g = 0; g < 4; ++g) {
                gm[g] = gmx[mr * 16 + qd * 4 + g];
                rowact |= (tmx[g] > fmaxf(m2[mr][g], gm[g]) - SKIP_MARGIN);
            }
            // publish (racy; losing a race only loses a skip, never correctness)
#pragma unroll
            for (int g = 0; g < 4; ++g)
                if (r == 0 && tmx[g] > gm[g]) gmx[mr * 16 + qd * 4 + g] = tmx[g];
            act[mr] = __any(rowact);
            if (!act[mr]) continue;   // tile globally negligible for all 16 rows

            // max update + O rescale (only when a new own-max appears)
            float alpha[4];
            bool nm = false;
#pragma unroll
            for (int g = 0; g < 4; ++g) nm |= (tmx[g] > m2[mr][g]);
            if (__any(nm)) {
#pragma unroll
                for (int g = 0; g < 4; ++g) {
                    float mn = fmaxf(m2[mr][g], tmx[g]);
                    alpha[g] = __builtin_amdgcn_exp2f(m2[mr][g] - mn);
                    m2[mr][g] = mn;
                }
#pragma unroll
                for (int n = 0; n < 8; ++n)
#pragma unroll
                    for (int g = 0; g < 4; ++g) oacc[mr][n][g] *= alpha[g];
            } else {
#pragma unroll
                for (int g = 0; g < 4; ++g) alpha[g] = 1.f;
            }

            float p[4][4], thr[4];
#pragma unroll
            for (int g = 0; g < 4; ++g) {
                float s = 0.f;
#pragma unroll
                for (int nb = 0; nb < 4; ++nb) {
                    p[nb][g] = __builtin_amdgcn_exp2f(cf[mr][nb][g] - m2[mr][g]);
                    s += p[nb][g];
                }
                s = row_sum16(s);
                lr[mr][g] = lr[mr][g] * alpha[g] + s;
                thr[g] = fmaxf(gm[g], m2[mr][g]) - DROP_MARGIN;
            }

            // dropout (hash only globally-significant entries); write P for PV
#pragma unroll
            for (int nb = 0; nb < 4; ++nb) {
#pragma unroll
                for (int g = 0; g < 4; ++g) {
                    if (__any(cf[mr][nb][g] > thr[g])) {
                        uint j = (uint)(blockRow0 + mr * 16 + qd * 4 + g) * (uint)NV
                               + (uint)(v0 + nb * 16 + r);
                        if (threefry_bits(j) >= KEEP_THRESH) p[nb][g] = 0.f;
                    }
                    // bf16 truncation (1 op; ~0.2% downward bias, within budget)
                    pls[(mr * 16 + qd * 4 + g) * PSTR + nb * 16 + r] =
                        (ushort)(__float_as_uint(p[nb][g]) >> 16);
                }
            }
        }

        if (act[0] | act[1]) {
            __asm__ volatile("s_waitcnt lgkmcnt(0)" ::: "memory");  // own-wave P visible
            // ---- PV(t): register-direct V frags, K=32 MFMAs per m-block ----
#pragma unroll
            for (int mr = 0; mr < 2; ++mr) {
                if (!act[mr]) continue;
#pragma unroll
                for (int kc2 = 0; kc2 < 2; ++kc2) {
                    short8 pa = *(const short8*)&pls[(mr * 16 + r) * PSTR + kc2 * 32 + qd * 8];
#pragma unroll
                    for (int n = 0; n < 8; ++n) {
                        short8 vb = *(const short8*)&tV[((kc2 * 8 + n) * 64 + lane) * 8];
                        oacc[mr][n] = __builtin_amdgcn_mfma_f32_16x16x32_bf16(pa, vb, oacc[mr][n], 0, 0, 0);
                    }
                }
            }
        }
    }

    // ---- 4-way end merge through the pls-aliased LDS region ----
    __syncthreads();   // all waves done with pls before obuf overwrites it
    if (wave >= 1) {
#pragma unroll
        for (int mr = 0; mr < 2; ++mr) {
            if (r == 0) {
#pragma unroll
                for (int g = 0; g < 4; ++g) {
                    mlbuf[wave - 1][mr * 16 + qd * 4 + g][0] = m2[mr][g];
                    mlbuf[wave - 1][mr * 16 + qd * 4 + g][1] = lr[mr][g];
                }
            }
#pragma unroll
            for (int n = 0; n < 8; ++n)
#pragma unroll
                for (int g = 0; g < 4; ++g)
                    smemf[(wave - 1) * 4096 + (mr * 16 + qd * 4 + g) * 128 + n * 16 + r] =
                        oacc[mr][n][g];
        }
    }
    __syncthreads();
    if (wave == 0) {
#pragma unroll
        for (int mr = 0; mr < 2; ++mr) {
            float a0[4], aw[3][4], inv[4];
#pragma unroll
            for (int g = 0; g < 4; ++g) {
                int row = mr * 16 + qd * 4 + g;
                float mn = m2[mr][g];
#pragma unroll
                for (int i = 0; i < 3; ++i) mn = fmaxf(mn, mlbuf[i][row][0]);
                a0[g] = __builtin_amdgcn_exp2f(m2[mr][g] - mn);
                float l = lr[mr][g] * a0[g];
#pragma unroll
                for (int i = 0; i < 3; ++i) {
                    aw[i][g] = __builtin_amdgcn_exp2f(mlbuf[i][row][0] - mn);
                    l += mlbuf[i][row][1] * aw[i][g];
                }
                inv[g] = 1.0f / (0.9f * l);
            }
#pragma unroll
            for (int n = 0; n < 8; ++n)
#pragma unroll
                for (int g = 0; g < 4; ++g) {
                    int row = mr * 16 + qd * 4 + g;
                    float o = oacc[mr][n][g] * a0[g];
#pragma unroll
                    for (int i = 0; i < 3; ++i)
                        o += smemf[i * 4096 + row * 128 + n * 16 + r] * aw[i][g];
                    Og[(size_t)(blockRow0 + row) * HD + n * 16 + r] = o * inv[g];
                }
        }
    }
}

// ============================ fallback (round-3, verified) ============================
__global__ __launch_bounds__(256)
void fa_mfma(const float* __restrict__ Qg, const float* __restrict__ Kg,
             const float* __restrict__ Vg, float* __restrict__ Og) {
    __shared__ ushort khi[64 * KSTR];
    __shared__ ushort klo[64 * KSTR];
    __shared__ ushort vt[128 * VSTR];
    __shared__ ushort plsf[4][16 * PSTR];

    const int tid  = threadIdx.x;
    const int wave = tid >> 6;
    const int lane = tid & 63;
    const int r    = lane & 15;
    const int qd   = lane >> 4;
    const int blockRow0 = blockIdx.x * 64;
    const int b = blockRow0 >> 12;
    const int waveRow0 = blockRow0 + wave * 16;
    const size_t kvbase = (size_t)b * NV * HD;

    short8 qfh[4], qfl[4];
    {
        const float* qp = Qg + (size_t)(waveRow0 + r) * HD + qd * 8;
#pragma unroll
        for (int kc = 0; kc < 4; ++kc) {
            float x[8];
            *(float4*)&x[0] = *(const float4*)(qp + kc * 32);
            *(float4*)&x[4] = *(const float4*)(qp + kc * 32 + 4);
#pragma unroll
            for (int j = 0; j < 8; ++j) {
                ushort h = bf16rne(x[j]);
                qfh[kc][j] = (short)h;
                qfl[kc][j] = (short)bf16rne(x[j] - bf2f(h));
            }
        }
    }

    floatx4 oacc[8];
#pragma unroll
    for (int n = 0; n < 8; ++n) oacc[n] = (floatx4){0.f, 0.f, 0.f, 0.f};
    float m2[4] = {-INFINITY, -INFINITY, -INFINITY, -INFINITY};
    float lr[4] = {0.f, 0.f, 0.f, 0.f};

    for (int v0 = 0; v0 < NV; v0 += 64) {
        __syncthreads();
#pragma unroll
        for (int i = 0; i < 8; ++i) {
            int f = i * 256 + tid;
            int v = f >> 5;
            int h = (f & 31) * 4;
            float4 kv = *(const float4*)(Kg + kvbase + (size_t)(v0 + v) * HD + h);
            ushort4 hh, ll;
            hh.x = bf16rne(kv.x); ll.x = bf16rne(kv.x - bf2f(hh.x));
            hh.y = bf16rne(kv.y); ll.y = bf16rne(kv.y - bf2f(hh.y));
            hh.z = bf16rne(kv.z); ll.z = bf16rne(kv.z - bf2f(hh.z));
            hh.w = bf16rne(kv.w); ll.w = bf16rne(kv.w - bf2f(hh.w));
            *(ushort4*)&khi[v * KSTR + h] = hh;
            *(ushort4*)&klo[v * KSTR + h] = ll;
        }
        {
            int hp = tid & 63, rp = tid >> 6;
            int h = hp * 2;
            const float* vpb = Vg + kvbase + (size_t)v0 * HD + h;
#pragma unroll
            for (int i = 0; i < 8; ++i) {
                int v = i * 8 + rp * 2;
                float2 a = *(const float2*)(vpb + (size_t)v * HD);
                float2 c = *(const float2*)(vpb + (size_t)(v + 1) * HD);
                uint w0 = (uint)bf16rne(a.x) | ((uint)bf16rne(c.x) << 16);
                uint w1 = (uint)bf16rne(a.y) | ((uint)bf16rne(c.y) << 16);
                *(uint*)&vt[h * VSTR + v]       = w0;
                *(uint*)&vt[(h + 1) * VSTR + v] = w1;
            }
        }
        __syncthreads();

        floatx4 cf[4];
#pragma unroll
        for (int nb = 0; nb < 4; ++nb) cf[nb] = (floatx4){0.f, 0.f, 0.f, 0.f};
#pragma unroll
        for (int kc = 0; kc < 4; ++kc) {
#pragma unroll
            for (int nb = 0; nb < 4; ++nb) {
                int off = (nb * 16 + r) * KSTR + kc * 32 + qd * 8;
                short8 kh = *(const short8*)&khi[off];
                short8 kl = *(const short8*)&klo[off];
                cf[nb] = __builtin_amdgcn_mfma_f32_16x16x32_bf16(qfh[kc], kh, cf[nb], 0, 0, 0);
                cf[nb] = __builtin_amdgcn_mfma_f32_16x16x32_bf16(qfh[kc], kl, cf[nb], 0, 0, 0);
                cf[nb] = __builtin_amdgcn_mfma_f32_16x16x32_bf16(qfl[kc], kh, cf[nb], 0, 0, 0);
            }
        }

        float ts[4][4], p[4][4];
#pragma unroll
        for (int nb = 0; nb < 4; ++nb)
#pragma unroll
            for (int g = 0; g < 4; ++g) ts[nb][g] = cf[nb][g] * SCL2E;

        float tsum[4], alpha[4], lnew[4];
#pragma unroll
        for (int g = 0; g < 4; ++g) {
            float tmx = fmaxf(fmaxf(ts[0][g], ts[1][g]), fmaxf(ts[2][g], ts[3][g]));
#pragma unroll
            for (int off = 1; off < 16; off <<= 1)
                tmx = fmaxf(tmx, __shfl_xor(tmx, off));
            float mn = fmaxf(m2[g], tmx);
            alpha[g] = __builtin_amdgcn_exp2f(m2[g] - mn);
            m2[g] = mn;
        }
#pragma unroll
        for (int g = 0; g < 4; ++g) {
            float s = 0.f;
#pragma unroll
            for (int nb = 0; nb < 4; ++nb) {
                p[nb][g] = __builtin_amdgcn_exp2f(ts[nb][g] - m2[g]);
                s += p[nb][g];
            }
#pragma unroll
            for (int off = 1; off < 16; off <<= 1)
                s += __shfl_xor(s, off);
            tsum[g] = s;
            lnew[g] = lr[g] * alpha[g] + s;
            lr[g] = lnew[g];
        }

        bool rowneed = false;
#pragma unroll
        for (int g = 0; g < 4; ++g) rowneed |= (tsum[g] > 1e-8f * lnew[g]);

        if (__any(rowneed)) {
#pragma unroll
            for (int n = 0; n < 8; ++n)
#pragma unroll
                for (int g = 0; g < 4; ++g) oacc[n][g] *= alpha[g];

#pragma unroll
            for (int nb = 0; nb < 4; ++nb) {
                bool nbneed = false;
#pragma unroll
                for (int g = 0; g < 4; ++g) nbneed |= (p[nb][g] > 1e-8f * lnew[g]);
                if (__any(nbneed)) {
#pragma unroll
                    for (int g = 0; g < 4; ++g) {
                        uint j = (uint)(waveRow0 + qd * 4 + g) * (uint)NV
                               + (uint)(v0 + nb * 16 + r);
                        if (threefry_bits(j) >= KEEP_THRESH) p[nb][g] = 0.f;
                    }
                }
#pragma unroll
                for (int g = 0; g < 4; ++g)
                    plsf[wave][(qd * 4 + g) * PSTR + nb * 16 + r] = bf16rne(p[nb][g]);
            }
            __asm__ volatile("s_waitcnt lgkmcnt(0)" ::: "memory");

#pragma unroll
            for (int kc2 = 0; kc2 < 2; ++kc2) {
                short8 pa = *(const short8*)&plsf[wave][r * PSTR + kc2 * 32 + qd * 8];
#pragma unroll
                for (int n = 0; n < 8; ++n) {
                    int off = (n * 16 + r) * VSTR + kc2 * 32 + qd * 8;
                    ushort4 u0 = *(const ushort4*)&vt[off];
                    ushort4 u1 = *(const ushort4*)&vt[off + 4];
                    short8 vb;
                    vb[0] = (short)u0.x; vb[1] = (short)u0.y; vb[2] = (short)u0.z; vb[3] = (short)u0.w;
                    vb[4] = (short)u1.x; vb[5] = (short)u1.y; vb[6] = (short)u1.z; vb[7] = (short)u1.w;
                    oacc[n] = __builtin_amdgcn_mfma_f32_16x16x32_bf16(pa, vb, oacc[n], 0, 0, 0);
                }
            }
        }
    }

    float inv[4];
#pragma unroll
    for (int g = 0; g < 4; ++g) inv[g] = 1.0f / (0.9f * lr[g]);
#pragma unroll
    for (int n = 0; n < 8; ++n)
#pragma unroll
        for (int g = 0; g < 4; ++g)
            Og[(size_t)(waveRow0 + qd * 4 + g) * HD + n * 16 + r] = oacc[n][g] * inv[g];
}

extern "C" void kernel_launch(void* const* d_in, const int* in_sizes, int n_in,
                              void* d_out, int out_size, void* d_ws, size_t ws_size,
                              hipStream_t stream) {
    (void)in_sizes; (void)n_in; (void)out_size;
    const float* Qg = (const float*)d_in[0];
    const float* Kg = (const float*)d_in[1];
    const float* Vg = (const float*)d_in[2];
    float* Og = (float*)d_out;
    if (ws_size >= WS_NEEDED) {
        ushort* W = (ushort*)d_ws;
        prepass<<<dim3(2048), 256, 0, stream>>>(Kg, Vg, W);
        fa_mfma7<<<dim3(NBATCH * NQ / 32), 256, 0, stream>>>(Qg, (const ushort*)W, Og);
    } else {
        fa_mfma<<<dim3(NBATCH * NQ / 64), 256, 0, stream>>>(Qg, Kg, Vg, Og);
    }
}

// Round 8
// 189.534 us; speedup vs baseline: 1.3440x; 1.0555x over previous
//
#include <hip/hip_runtime.h>
#include <stdint.h>

// B=4, Q=4096, V=4096, H=128, fp32 in/out
#define NBATCH 4
#define NQ 4096
#define NV 4096
#define HD 128

// SCALE * log2(e): scores scaled into exp2 domain (folded into Q fragments)
#define SCL2E ((float)(11.31370849898476 * 1.4426950408889634))

// keep  <=>  bits < 0.9f in fixed point (0.9f = 7549747 * 2^-23)
#define KEEP_THRESH 3865470464u

// skip a (tile,16-row) granule when its max is this far below the best seen
// (64 * 2^-27 < 1e-6, and final per-row l >= 1  =>  contribution < 1e-6 rel.)
#define SKIP_MARGIN 27.0f
// hash dropout only for entries within this of the best seen max
// (2^-20 ~ 1e-6 of the final sum)
#define DROP_MARGIN 20.0f

// --- ws layout (prepass output), FRAG-MAJOR (verified) ---
// per (batch,tile) record: [khi 8192 ush][klo 8192 ush][vt 8192 ush] = 48 KB
// K chunk (kc,nb,lane): (kc*4+nb)*64+lane holds K[v=nb*16+r][kc*32+qd*8..+8]
// V chunk (kc2,n,lane): (kc2*8+n)*64+lane holds V^T[h=n*16+r][kc2*32+qd*8..+8]
#define TILE_USH 24576
#define WS_NEEDED ((size_t)NBATCH * 64 * TILE_USH * 2)       // 12,582,912 B

#define PSTR 72    // pls row stride (ushorts)
#define VLSTR 142  // prepass LDS v-tile stride (ushorts)

// --- fallback path constants (round-3 kernel, verified passing) ---
#define KSTR 144
#define VSTR 76

// XCD-cluster block swizzle (bijective on [0,512): 512 = 8 XCDs x 64).
// blockIdx -> XCD is round-robin (%8) on MI355X, so original consecutive-id
// blocks of ONE batch spread over ALL 8 XCDs: every XCD's 4MB L2 serves the
// full 12MB W working set -> thrash (r4 proved the fix: batch->XCD clustering
// cut FETCH 60->16.6MB). swz gives XCD x the 64 consecutive blocks of batch
// x>>1: one 3MB W slice per L2. Perf heuristic only; bijection = correctness
// independent of the actual mapping.
#define XSWZ(b) ((((b) & 7) << 6) | ((b) >> 3))

typedef __attribute__((ext_vector_type(8))) short short8;   // 8 bf16 (MFMA A/B frag)
typedef __attribute__((ext_vector_type(4))) float floatx4;  // MFMA C/D frag
typedef unsigned int uint;
typedef unsigned short ushort;

__device__ __forceinline__ ushort bf16rne(float f) {
    uint u = __float_as_uint(f);
    u = (u + 0x7fffu + ((u >> 16) & 1u)) >> 16;
    return (ushort)u;
}
__device__ __forceinline__ float bf2f(ushort h) {
    return __uint_as_float(((uint)h) << 16);
}

// ---- DPP 16-lane reductions (VALU-only, no DS pipe) ----
template <int CTRL>
__device__ __forceinline__ float dppmov(float x) {
    return __int_as_float(__builtin_amdgcn_update_dpp(
        0, __float_as_int(x), CTRL, 0xF, 0xF, true));
}
__device__ __forceinline__ float row_max16(float x) {
    x = fmaxf(x, dppmov<0xB1>(x));    // quad_perm xor1
    x = fmaxf(x, dppmov<0x4E>(x));    // quad_perm xor2
    x = fmaxf(x, dppmov<0x141>(x));   // row_half_mirror
    x = fmaxf(x, dppmov<0x140>(x));   // row_mirror
    return x;
}
__device__ __forceinline__ float row_sum16(float x) {
    x += dppmov<0xB1>(x);
    x += dppmov<0x4E>(x);
    x += dppmov<0x141>(x);
    x += dppmov<0x140>(x);
    return x;
}

__device__ __forceinline__ uint rotl(uint x, int r) { return (x << r) | (x >> (32 - r)); }

// JAX threefry2x32 partitionable path, key=(0,42): bits = y0 ^ y1 of hash of 64-bit counter j
__device__ __forceinline__ uint threefry_bits(uint j) {
    uint x0 = 0u;   // counter hi word (all j < 2^32)
    uint x1 = j;
    const uint k0 = 0u, k1 = 42u, k2 = 0u ^ 42u ^ 0x1BD11BDAu;
    x0 += k0; x1 += k1;
#define TFR4(a,b,c,d) \
    x0 += x1; x1 = rotl(x1, a); x1 ^= x0; \
    x0 += x1; x1 = rotl(x1, b); x1 ^= x0; \
    x0 += x1; x1 = rotl(x1, c); x1 ^= x0; \
    x0 += x1; x1 = rotl(x1, d); x1 ^= x0;
    TFR4(13, 15, 26, 6)
    x0 += k1; x1 += k2 + 1u;
    TFR4(17, 29, 16, 24)
    x0 += k2; x1 += k0 + 2u;
    TFR4(13, 15, 26, 6)
    x0 += k0; x1 += k1 + 3u;
    TFR4(17, 29, 16, 24)
    x0 += k1; x1 += k2 + 4u;
    TFR4(13, 15, 26, 6)
    x0 += k2; x1 += k0 + 5u;
#undef TFR4
    return x0 ^ x1;
}

// ============================ prepass (r3 body + XCD swizzle) ============================
// Swizzled so batch-b records are WRITTEN by the same XCD pair {2b,2b+1} whose
// blocks later READ them in fa_mfma7 (warm-L2 handoff if L2 survives the
// kernel boundary; pure locality win regardless).
__global__ __launch_bounds__(256)
void prepass(const float* __restrict__ Kg, const float* __restrict__ Vg,
             ushort* __restrict__ W) {
    __shared__ ushort vls[64 * VLSTR];
    const int swz  = XSWZ((int)blockIdx.x);
    const int rec  = swz >> 1;
    const int half = swz & 1;
    const int bb = rec >> 6;
    const int t  = rec & 63;
    const int v0 = t * 64;
    const size_t kvbase = (size_t)bb * NV * HD;
    ushort* dst = W + ((size_t)bb * 64 + t) * TILE_USH;
    const int tid = threadIdx.x;

    if (half == 0) {
        ushort* dkh = dst;
        ushort* dkl = dst + 8192;
#pragma unroll
        for (int i = 0; i < 4; ++i) {
            int lc = i * 256 + tid;
            int v = lc >> 4, c = lc & 15;
            const float* src = Kg + kvbase + (size_t)(v0 + v) * HD + c * 8;
            float x[8];
            *(float4*)&x[0] = *(const float4*)src;
            *(float4*)&x[4] = *(const float4*)(src + 4);
            uint H[4], L[4];
#pragma unroll
            for (int k = 0; k < 4; ++k) {
                ushort h0 = bf16rne(x[2 * k]),     h1 = bf16rne(x[2 * k + 1]);
                ushort l0 = bf16rne(x[2 * k] - bf2f(h0));
                ushort l1 = bf16rne(x[2 * k + 1] - bf2f(h1));
                H[k] = (uint)h0 | ((uint)h1 << 16);
                L[k] = (uint)l0 | ((uint)l1 << 16);
            }
            int pos = (((c >> 2) * 4 + (v >> 4)) * 64 + (c & 3) * 16 + (v & 15)) * 8;
            *(uint4*)&dkh[pos] = *(uint4*)H;
            *(uint4*)&dkl[pos] = *(uint4*)L;
        }
    } else {
        ushort* dvt = dst + 16384;
#pragma unroll
        for (int i = 0; i < 8; ++i) {
            int idx = i * 256 + tid;
            int v = idx >> 5, hq = idx & 31;
            float4 a = *(const float4*)(Vg + kvbase + (size_t)(v0 + v) * HD + hq * 4);
            uint w0 = (uint)bf16rne(a.x) | ((uint)bf16rne(a.y) << 16);
            uint w1 = (uint)bf16rne(a.z) | ((uint)bf16rne(a.w) << 16);
            *(uint*)&vls[v * VLSTR + hq * 4]     = w0;
            *(uint*)&vls[v * VLSTR + hq * 4 + 2] = w1;
        }
        __syncthreads();
#pragma unroll
        for (int i = 0; i < 4; ++i) {
            int lc = i * 256 + tid;
            int h = lc >> 3, c2 = lc & 7;
            uint Wd[4];
#pragma unroll
            for (int m = 0; m < 8; m += 2) {
                ushort a  = vls[(c2 * 8 + m) * VLSTR + h];
                ushort b2 = vls[(c2 * 8 + m + 1) * VLSTR + h];
                Wd[m >> 1] = (uint)a | ((uint)b2 << 16);
            }
            int pos = (((c2 >> 2) * 8 + (h >> 4)) * 64 + (c2 & 3) * 16 + (h & 15)) * 8;
            *(uint4*)&dvt[pos] = *(uint4*)Wd;
        }
    }
}

// ============================ main (fast path, r3 body + XCD swizzle) ============================
// grid 512 x 256 threads (4 waves), 32 q-rows/block, tiles t = wave (mod 4),
// no barriers in the K-loop, all MFMA operands register-direct from frag-major W.
//
// REGISTER BUDGET (hard-won): __launch_bounds__(256,2) = 2 waves/SIMD = 256
// unified VGPRs/wave. Live state ~190: fits at w=2 (128 arch VGPRs, zero
// spill), spills catastrophically at w=3/w=4 (r1/r2: 0.8-1.6 GB scratch).
// STRUCTURAL LESSONS (r4-r7): 16 rows/block regresses (amortization); manual
// QK pipelining regresses (compiler hoists loads better); hh-screening
// regresses (extra dependent phase on the latency-bound critical path);
// prepass grid split is neutral. Cross-session noise on identical code is
// ~13% (r3 139us vs r7 158us) — only large deltas are meaningful.
//
// NEW vs r3 (ONLY change): XSWZ block swizzle clustering each batch's blocks
// on one XCD pair so each L2 holds exactly one 3MB W slice instead of all
// 12MB (mechanism proven by r4's FETCH 60->16.6MB drop).
// Fragment layouts (gfx950 mfma_f32_16x16x32_bf16, m89/m120-verified):
//   A: lane holds A[m = lane&15][k = (lane>>4)*8 + j]
//   B: lane holds B[k = (lane>>4)*8 + j][n = lane&15]
//   C/D: lane holds D[row = (lane>>4)*4 + reg][col = lane&15]
__global__ __launch_bounds__(256, 2)
void fa_mfma7(const float* __restrict__ Qg, const ushort* __restrict__ Wk,
              float* __restrict__ Og) {
    __shared__ __align__(16) float smemf[12288];  // 48 KB: pls (loop) | 3x obuf (epilogue)
    __shared__ float mlbuf[3][32][2];             // waves 1-3 partial (m, l)
    __shared__ float gmx[32];                     // per-row best max seen (racy)

    const int tid  = threadIdx.x;
    const int wave = tid >> 6;    // 0..3, tile phase
    const int lane = tid & 63;
    const int r    = lane & 15;
    const int qd   = lane >> 4;
    const int blockRow0 = XSWZ((int)blockIdx.x) * 32;
    const int b = blockRow0 >> 12;
    const ushort* kvw = Wk + (size_t)b * 64 * TILE_USH;
    ushort* pls = (ushort*)smemf + wave * (32 * PSTR);   // per-wave P region

    if (tid < 32) gmx[tid] = -1e30f;

    // Q -> A-fragments for both 16-row m-blocks, PRE-SCALED by SCL2E,
    // hi/lo bf16 split, registers.
    short8 qfh[2][4], qfl[2][4];
#pragma unroll
    for (int mr = 0; mr < 2; ++mr) {
        const float* qp = Qg + (size_t)(blockRow0 + mr * 16 + r) * HD + qd * 8;
#pragma unroll
        for (int kc = 0; kc < 4; ++kc) {
            float x[8];
            *(float4*)&x[0] = *(const float4*)(qp + kc * 32);
            *(float4*)&x[4] = *(const float4*)(qp + kc * 32 + 4);
#pragma unroll
            for (int j = 0; j < 8; ++j) {
                float xs = x[j] * SCL2E;
                ushort h = bf16rne(xs);
                qfh[mr][kc][j] = (short)h;
                qfl[mr][kc][j] = (short)bf16rne(xs - bf2f(h));
            }
        }
    }

    floatx4 oacc[2][8];
#pragma unroll
    for (int mr = 0; mr < 2; ++mr)
#pragma unroll
        for (int n = 0; n < 8; ++n) oacc[mr][n] = (floatx4){0.f, 0.f, 0.f, 0.f};
    float m2[2][4], lr[2][4];
#pragma unroll
    for (int mr = 0; mr < 2; ++mr)
#pragma unroll
        for (int g = 0; g < 4; ++g) { m2[mr][g] = -1e30f; lr[mr][g] = 0.f; }

    __syncthreads();   // gmx initialized

    for (int t = wave; t < 64; t += 4) {
        const ushort* tK = kvw + (size_t)t * TILE_USH;
        const ushort* tV = tK + 16384;
        const int v0 = t * 64;

        // ---- QK^T(t): register-direct loads, 3-term bf16-split, both m-blocks ----
        floatx4 cf[2][4];
#pragma unroll
        for (int mr = 0; mr < 2; ++mr)
#pragma unroll
            for (int nb = 0; nb < 4; ++nb) cf[mr][nb] = (floatx4){0.f, 0.f, 0.f, 0.f};
#pragma unroll
        for (int kc = 0; kc < 4; ++kc) {
            short8 kh[4], kl[4];
#pragma unroll
            for (int nb = 0; nb < 4; ++nb) {
                int off = ((kc * 4 + nb) * 64 + lane) * 8;
                kh[nb] = *(const short8*)&tK[off];
                kl[nb] = *(const short8*)&tK[8192 + off];
            }
#pragma unroll
            for (int nb = 0; nb < 4; ++nb)
#pragma unroll
                for (int mr = 0; mr < 2; ++mr) {
                    cf[mr][nb] = __builtin_amdgcn_mfma_f32_16x16x32_bf16(qfh[mr][kc], kh[nb], cf[mr][nb], 0, 0, 0);
                    cf[mr][nb] = __builtin_amdgcn_mfma_f32_16x16x32_bf16(qfh[mr][kc], kl[nb], cf[mr][nb], 0, 0, 0);
                    cf[mr][nb] = __builtin_amdgcn_mfma_f32_16x16x32_bf16(qfl[mr][kc], kh[nb], cf[mr][nb], 0, 0, 0);
                }
        }

        // ---- online softmax (exp2 domain, scores pre-scaled), per m-block ----
        bool act[2];
#pragma unroll
        for (int mr = 0; mr < 2; ++mr) {
            float tmx[4], gm[4];
#pragma unroll
            for (int g = 0; g < 4; ++g) {
                float v = fmaxf(fmaxf(cf[mr][0][g], cf[mr][1][g]),
                                fmaxf(cf[mr][2][g], cf[mr][3][g]));
                tmx[g] = row_max16(v);
            }
            bool rowact = false;
#pragma unroll
            for (int g = 0; g < 4; ++g) {
                gm[g] = gmx[mr * 16 + qd * 4 + g];
                rowact |= (tmx[g] > fmaxf(m2[mr][g], gm[g]) - SKIP_MARGIN);
            }
            // publish (racy; losing a race only loses a skip, never correctness)
#pragma unroll
            for (int g = 0; g < 4; ++g)
                if (r == 0 && tmx[g] > gm[g]) gmx[mr * 16 + qd * 4 + g] = tmx[g];
            act[mr] = __any(rowact);
            if (!act[mr]) continue;   // tile globally negligible for all 16 rows

            // max update + O rescale (only when a new own-max appears)
            float alpha[4];
            bool nm = false;
#pragma unroll
            for (int g = 0; g < 4; ++g) nm |= (tmx[g] > m2[mr][g]);
            if (__any(nm)) {
#pragma unroll
                for (int g = 0; g < 4; ++g) {
                    float mn = fmaxf(m2[mr][g], tmx[g]);
                    alpha[g] = __builtin_amdgcn_exp2f(m2[mr][g] - mn);
                    m2[mr][g] = mn;
                }
#pragma unroll
                for (int n = 0; n < 8; ++n)
#pragma unroll
                    for (int g = 0; g < 4; ++g) oacc[mr][n][g] *= alpha[g];
            } else {
#pragma unroll
                for (int g = 0; g < 4; ++g) alpha[g] = 1.f;
            }

            float p[4][4], thr[4];
#pragma unroll
            for (int g = 0; g < 4; ++g) {
                float s = 0.f;
#pragma unroll
                for (int nb = 0; nb < 4; ++nb) {
                    p[nb][g] = __builtin_amdgcn_exp2f(cf[mr][nb][g] - m2[mr][g]);
                    s += p[nb][g];
                }
                s = row_sum16(s);
                lr[mr][g] = lr[mr][g] * alpha[g] + s;
                thr[g] = fmaxf(gm[g], m2[mr][g]) - DROP_MARGIN;
            }

            // dropout (hash only globally-significant entries); write P for PV
#pragma unroll
            for (int nb = 0; nb < 4; ++nb) {
#pragma unroll
                for (int g = 0; g < 4; ++g) {
                    if (__any(cf[mr][nb][g] > thr[g])) {
                        uint j = (uint)(blockRow0 + mr * 16 + qd * 4 + g) * (uint)NV
                               + (uint)(v0 + nb * 16 + r);
                        if (threefry_bits(j) >= KEEP_THRESH) p[nb][g] = 0.f;
                    }
                    // bf16 truncation (1 op; ~0.2% downward bias, within budget)
                    pls[(mr * 16 + qd * 4 + g) * PSTR + nb * 16 + r] =
                        (ushort)(__float_as_uint(p[nb][g]) >> 16);
                }
            }
        }

        if (act[0] | act[1]) {
            __asm__ volatile("s_waitcnt lgkmcnt(0)" ::: "memory");  // own-wave P visible
            // ---- PV(t): register-direct V frags, K=32 MFMAs per m-block ----
#pragma unroll
            for (int mr = 0; mr < 2; ++mr) {
                if (!act[mr]) continue;
#pragma unroll
                for (int kc2 = 0; kc2 < 2; ++kc2) {
                    short8 pa = *(const short8*)&pls[(mr * 16 + r) * PSTR + kc2 * 32 + qd * 8];
#pragma unroll
                    for (int n = 0; n < 8; ++n) {
                        short8 vb = *(const short8*)&tV[((kc2 * 8 + n) * 64 + lane) * 8];
                        oacc[mr][n] = __builtin_amdgcn_mfma_f32_16x16x32_bf16(pa, vb, oacc[mr][n], 0, 0, 0);
                    }
                }
            }
        }
    }

    // ---- 4-way end merge through the pls-aliased LDS region ----
    __syncthreads();   // all waves done with pls before obuf overwrites it
    if (wave >= 1) {
#pragma unroll
        for (int mr = 0; mr < 2; ++mr) {
            if (r == 0) {
#pragma unroll
                for (int g = 0; g < 4; ++g) {
                    mlbuf[wave - 1][mr * 16 + qd * 4 + g][0] = m2[mr][g];
                    mlbuf[wave - 1][mr * 16 + qd * 4 + g][1] = lr[mr][g];
                }
            }
#pragma unroll
            for (int n = 0; n < 8; ++n)
#pragma unroll
                for (int g = 0; g < 4; ++g)
                    smemf[(wave - 1) * 4096 + (mr * 16 + qd * 4 + g) * 128 + n * 16 + r] =
                        oacc[mr][n][g];
        }
    }
    __syncthreads();
    if (wave == 0) {
#pragma unroll
        for (int mr = 0; mr < 2; ++mr) {
            float a0[4], aw[3][4], inv[4];
#pragma unroll
            for (int g = 0; g < 4; ++g) {
                int row = mr * 16 + qd * 4 + g;
                float mn = m2[mr][g];
#pragma unroll
                for (int i = 0; i < 3; ++i) mn = fmaxf(mn, mlbuf[i][row][0]);
                a0[g] = __builtin_amdgcn_exp2f(m2[mr][g] - mn);
                float l = lr[mr][g] * a0[g];
#pragma unroll
                for (int i = 0; i < 3; ++i) {
                    aw[i][g] = __builtin_amdgcn_exp2f(mlbuf[i][row][0] - mn);
                    l += mlbuf[i][row][1] * aw[i][g];
                }
                inv[g] = 1.0f / (0.9f * l);
            }
#pragma unroll
            for (int n = 0; n < 8; ++n)
#pragma unroll
                for (int g = 0; g < 4; ++g) {
                    int row = mr * 16 + qd * 4 + g;
                    float o = oacc[mr][n][g] * a0[g];
#pragma unroll
                    for (int i = 0; i < 3; ++i)
                        o += smemf[i * 4096 + row * 128 + n * 16 + r] * aw[i][g];
                    Og[(size_t)(blockRow0 + row) * HD + n * 16 + r] = o * inv[g];
                }
        }
    }
}

// ============================ fallback (round-3, verified) ============================
__global__ __launch_bounds__(256)
void fa_mfma(const float* __restrict__ Qg, const float* __restrict__ Kg,
             const float* __restrict__ Vg, float* __restrict__ Og) {
    __shared__ ushort khi[64 * KSTR];
    __shared__ ushort klo[64 * KSTR];
    __shared__ ushort vt[128 * VSTR];
    __shared__ ushort plsf[4][16 * PSTR];

    const int tid  = threadIdx.x;
    const int wave = tid >> 6;
    const int lane = tid & 63;
    const int r    = lane & 15;
    const int qd   = lane >> 4;
    const int blockRow0 = blockIdx.x * 64;
    const int b = blockRow0 >> 12;
    const int waveRow0 = blockRow0 + wave * 16;
    const size_t kvbase = (size_t)b * NV * HD;

    short8 qfh[4], qfl[4];
    {
        const float* qp = Qg + (size_t)(waveRow0 + r) * HD + qd * 8;
#pragma unroll
        for (int kc = 0; kc < 4; ++kc) {
            float x[8];
            *(float4*)&x[0] = *(const float4*)(qp + kc * 32);
            *(float4*)&x[4] = *(const float4*)(qp + kc * 32 + 4);
#pragma unroll
            for (int j = 0; j < 8; ++j) {
                ushort h = bf16rne(x[j]);
                qfh[kc][j] = (short)h;
                qfl[kc][j] = (short)bf16rne(x[j] - bf2f(h));
            }
        }
    }

    floatx4 oacc[8];
#pragma unroll
    for (int n = 0; n < 8; ++n) oacc[n] = (floatx4){0.f, 0.f, 0.f, 0.f};
    float m2[4] = {-INFINITY, -INFINITY, -INFINITY, -INFINITY};
    float lr[4] = {0.f, 0.f, 0.f, 0.f};

    for (int v0 = 0; v0 < NV; v0 += 64) {
        __syncthreads();
#pragma unroll
        for (int i = 0; i < 8; ++i) {
            int f = i * 256 + tid;
            int v = f >> 5;
            int h = (f & 31) * 4;
            float4 kv = *(const float4*)(Kg + kvbase + (size_t)(v0 + v) * HD + h);
            ushort4 hh, ll;
            hh.x = bf16rne(kv.x); ll.x = bf16rne(kv.x - bf2f(hh.x));
            hh.y = bf16rne(kv.y); ll.y = bf16rne(kv.y - bf2f(hh.y));
            hh.z = bf16rne(kv.z); ll.z = bf16rne(kv.z - bf2f(hh.z));
            hh.w = bf16rne(kv.w); ll.w = bf16rne(kv.w - bf2f(hh.w));
            *(ushort4*)&khi[v * KSTR + h] = hh;
            *(ushort4*)&klo[v * KSTR + h] = ll;
        }
        {
            int hp = tid & 63, rp = tid >> 6;
            int h = hp * 2;
            const float* vpb = Vg + kvbase + (size_t)v0 * HD + h;
#pragma unroll
            for (int i = 0; i < 8; ++i) {
                int v = i * 8 + rp * 2;
                float2 a = *(const float2*)(vpb + (size_t)v * HD);
                float2 c = *(const float2*)(vpb + (size_t)(v + 1) * HD);
                uint w0 = (uint)bf16rne(a.x) | ((uint)bf16rne(c.x) << 16);
                uint w1 = (uint)bf16rne(a.y) | ((uint)bf16rne(c.y) << 16);
                *(uint*)&vt[h * VSTR + v]       = w0;
                *(uint*)&vt[(h + 1) * VSTR + v] = w1;
            }
        }
        __syncthreads();

        floatx4 cf[4];
#pragma unroll
        for (int nb = 0; nb < 4; ++nb) cf[nb] = (floatx4){0.f, 0.f, 0.f, 0.f};
#pragma unroll
        for (int kc = 0; kc < 4; ++kc) {
#pragma unroll
            for (int nb = 0; nb < 4; ++nb) {
                int off = (nb * 16 + r) * KSTR + kc * 32 + qd * 8;
                short8 kh = *(const short8*)&khi[off];
                short8 kl = *(const short8*)&klo[off];
                cf[nb] = __builtin_amdgcn_mfma_f32_16x16x32_bf16(qfh[kc], kh, cf[nb], 0, 0, 0);
                cf[nb] = __builtin_amdgcn_mfma_f32_16x16x32_bf16(qfh[kc], kl, cf[nb], 0, 0, 0);
                cf[nb] = __builtin_amdgcn_mfma_f32_16x16x32_bf16(qfl[kc], kh, cf[nb], 0, 0, 0);
            }
        }

        float ts[4][4], p[4][4];
#pragma unroll
        for (int nb = 0; nb < 4; ++nb)
#pragma unroll
            for (int g = 0; g < 4; ++g) ts[nb][g] = cf[nb][g] * SCL2E;

        float tsum[4], alpha[4], lnew[4];
#pragma unroll
        for (int g = 0; g < 4; ++g) {
            float tmx = fmaxf(fmaxf(ts[0][g], ts[1][g]), fmaxf(ts[2][g], ts[3][g]));
#pragma unroll
            for (int off = 1; off < 16; off <<= 1)
                tmx = fmaxf(tmx, __shfl_xor(tmx, off));
            float mn = fmaxf(m2[g], tmx);
            alpha[g] = __builtin_amdgcn_exp2f(m2[g] - mn);
            m2[g] = mn;
        }
#pragma unroll
        for (int g = 0; g < 4; ++g) {
            float s = 0.f;
#pragma unroll
            for (int nb = 0; nb < 4; ++nb) {
                p[nb][g] = __builtin_amdgcn_exp2f(ts[nb][g] - m2[g]);
                s += p[nb][g];
            }
#pragma unroll
            for (int off = 1; off < 16; off <<= 1)
                s += __shfl_xor(s, off);
            tsum[g] = s;
            lnew[g] = lr[g] * alpha[g] + s;
            lr[g] = lnew[g];
        }

        bool rowneed = false;
#pragma unroll
        for (int g = 0; g < 4; ++g) rowneed |= (tsum[g] > 1e-8f * lnew[g]);

        if (__any(rowneed)) {
#pragma unroll
            for (int n = 0; n < 8; ++n)
#pragma unroll
                for (int g = 0; g < 4; ++g) oacc[n][g] *= alpha[g];

#pragma unroll
            for (int nb = 0; nb < 4; ++nb) {
                bool nbneed = false;
#pragma unroll
                for (int g = 0; g < 4; ++g) nbneed |= (p[nb][g] > 1e-8f * lnew[g]);
                if (__any(nbneed)) {
#pragma unroll
                    for (int g = 0; g < 4; ++g) {
                        uint j = (uint)(waveRow0 + qd * 4 + g) * (uint)NV
                               + (uint)(v0 + nb * 16 + r);
                        if (threefry_bits(j) >= KEEP_THRESH) p[nb][g] = 0.f;
                    }
                }
#pragma unroll
                for (int g = 0; g < 4; ++g)
                    plsf[wave][(qd * 4 + g) * PSTR + nb * 16 + r] = bf16rne(p[nb][g]);
            }
            __asm__ volatile("s_waitcnt lgkmcnt(0)" ::: "memory");

#pragma unroll
            for (int kc2 = 0; kc2 < 2; ++kc2) {
                short8 pa = *(const short8*)&plsf[wave][r * PSTR + kc2 * 32 + qd * 8];
#pragma unroll
                for (int n = 0; n < 8; ++n) {
                    int off = (n * 16 + r) * VSTR + kc2 * 32 + qd * 8;
                    ushort4 u0 = *(const ushort4*)&vt[off];
                    ushort4 u1 = *(const ushort4*)&vt[off + 4];
                    short8 vb;
                    vb[0] = (short)u0.x; vb[1] = (short)u0.y; vb[2] = (short)u0.z; vb[3] = (short)u0.w;
                    vb[4] = (short)u1.x; vb[5] = (short)u1.y; vb[6] = (short)u1.z; vb[7] = (short)u1.w;
                    oacc[n] = __builtin_amdgcn_mfma_f32_16x16x32_bf16(pa, vb, oacc[n], 0, 0, 0);
                }
            }
        }
    }

    float inv[4];
#pragma unroll
    for (int g = 0; g < 4; ++g) inv[g] = 1.0f / (0.9f * lr[g]);
#pragma unroll
    for (int n = 0; n < 8; ++n)
#pragma unroll
        for (int g = 0; g < 4; ++g)
            Og[(size_t)(waveRow0 + qd * 4 + g) * HD + n * 16 + r] = oacc[n][g] * inv[g];
}

extern "C" void kernel_launch(void* const* d_in, const int* in_sizes, int n_in,
                              void* d_out, int out_size, void* d_ws, size_t ws_size,
                              hipStream_t stream) {
    (void)in_sizes; (void)n_in; (void)out_size;
    const float* Qg = (const float*)d_in[0];
    const float* Kg = (const float*)d_in[1];
    const float* Vg = (const float*)d_in[2];
    float* Og = (float*)d_out;
    if (ws_size >= WS_NEEDED) {
        ushort* W = (ushort*)d_ws;
        prepass<<<dim3(512), 256, 0, stream>>>(Kg, Vg, W);
        fa_mfma7<<<dim3(NBATCH * NQ / 32), 256, 0, stream>>>(Qg, (const ushort*)W, Og);
    } else {
        fa_mfma<<<dim3(NBATCH * NQ / 64), 256, 0, stream>>>(Qg, Kg, Vg, Og);
    }
}